// Round 1
// baseline (1404.189 us; speedup 1.0000x reference)
//
#include <hip/hip_runtime.h>
#include <hip/hip_bf16.h>
#include <stdint.h>
#include <stddef.h>

// ---------------------------------------------------------------------------
// Problem dims
// ---------------------------------------------------------------------------
constexpr int BATCH = 512, TSTEPS = 16, DIM = 2500, HID = 300;
constexpr int BT = BATCH * TSTEPS;   // 8192
constexpr int GP = 1280;             // padded gate count (4*300 -> 1280)
constexpr int KP = 320;              // padded hidden (300 -> 320)
constexpr int DP = 2560;             // padded DIM (2500 -> 2560)

// ---------------------------------------------------------------------------
// Workspace layout (bytes)
// ---------------------------------------------------------------------------
constexpr size_t OFF_XPROJ = 0;                                  // [8192][1280] f32
constexpr size_t SZ_XPROJ  = (size_t)BT * GP * 4;
constexpr size_t OFF_XBF   = OFF_XPROJ + SZ_XPROJ;               // [8192][2560] bf16
constexpr size_t SZ_XBF    = (size_t)BT * DP * 2;
constexpr size_t OFF_WIH1  = OFF_XBF + SZ_XBF;                   // [1280][2560] bf16 (perm)
constexpr size_t SZ_WIH1   = (size_t)GP * DP * 2;
constexpr size_t OFF_WHH   = OFF_WIH1 + SZ_WIH1;                 // 3x [1280][320] bf16 (perm)
constexpr size_t SZ_WHH1   = (size_t)GP * KP * 2;
constexpr size_t OFF_WIH23 = OFF_WHH + 3 * SZ_WHH1;              // 2x [1280][320] bf16 (perm)
constexpr size_t OFF_WFC   = OFF_WIH23 + 2 * SZ_WHH1;            // [2560][320] bf16
constexpr size_t SZ_WFC    = (size_t)DP * KP * 2;
constexpr size_t OFF_BIAS  = OFF_WFC + SZ_WFC;                   // 3x [1280] f32 (perm bih+bhh)
constexpr size_t OFF_H1    = OFF_BIAS + 3 * GP * 4;              // [8192][320] bf16
constexpr size_t SZ_H      = (size_t)BT * KP * 2;
constexpr size_t OFF_H2    = OFF_H1 + SZ_H;
constexpr size_t OFF_H3    = OFF_H2 + SZ_H;
constexpr size_t OFF_OUTB  = OFF_H3 + SZ_H;                      // [512][2500] f32
constexpr size_t OFF_SUMS  = OFF_OUTB + (size_t)BATCH * DIM * 4; // [2][512] f32
constexpr size_t WS_NEED   = OFF_SUMS + 2 * BATCH * 4;

typedef __attribute__((ext_vector_type(8))) short short8;
typedef __attribute__((ext_vector_type(4))) float f32x4;

__device__ __forceinline__ unsigned short f2bf(float f) {
  __hip_bfloat16 h = __float2bfloat16(f);
  return *reinterpret_cast<unsigned short*>(&h);
}

__device__ __forceinline__ void gload_lds16(const void* g, void* l) {
  __builtin_amdgcn_global_load_lds(
      (const __attribute__((address_space(1))) unsigned int*)g,
      (__attribute__((address_space(3))) unsigned int*)l,
      16, 0, 0);
}

__device__ __forceinline__ float sigm(float x) { return 1.f / (1.f + __expf(-x)); }
__device__ __forceinline__ float tanh_(float x) {
  x = fminf(fmaxf(x, -30.f), 30.f);
  float e = __expf(2.f * x);
  return (e - 1.f) / (e + 1.f);
}

// ---------------------------------------------------------------------------
// K0a: x f32 -> bf16 padded [8192][2560]
// ---------------------------------------------------------------------------
__global__ __launch_bounds__(256) void k_prep_x(const float* __restrict__ x,
                                                unsigned short* __restrict__ xbf) {
  int idx = blockIdx.x * 256 + threadIdx.x;       // one thread = 8 outputs
  int row = idx / (DP / 8);
  int k8  = (idx % (DP / 8)) * 8;
  if (row >= BT) return;
  short8 v;
  if (k8 + 8 <= DIM) {
    const float* src = x + (size_t)row * DIM + k8;
    float4 f0 = *(const float4*)(src);
    float4 f1 = *(const float4*)(src + 4);
    v[0] = f2bf(f0.x); v[1] = f2bf(f0.y); v[2] = f2bf(f0.z); v[3] = f2bf(f0.w);
    v[4] = f2bf(f1.x); v[5] = f2bf(f1.y); v[6] = f2bf(f1.z); v[7] = f2bf(f1.w);
  } else {
#pragma unroll
    for (int j = 0; j < 8; ++j) {
      int k = k8 + j;
      float f = (k < DIM) ? x[(size_t)row * DIM + k] : 0.f;
      v[j] = f2bf(f);
    }
  }
  *reinterpret_cast<short8*>(xbf + (size_t)row * DP + k8) = v;
}

// ---------------------------------------------------------------------------
// K0b: all weights -> bf16, gate-permuted (n' = 4*j + g), padded; bias sums; zero sums
// ---------------------------------------------------------------------------
constexpr long PW_R1 = (long)GP * DP;          // Wih1p
constexpr long PW_R2 = 3L * GP * KP;           // Whh1..3
constexpr long PW_R3 = 2L * GP * KP;           // Wih2,3
constexpr long PW_R4 = (long)DP * KP;          // Wfc
constexpr long PW_R5 = 3L * GP;                // biases
constexpr long PW_R6 = 2L * BATCH;             // sums zero
constexpr long PW_TOTAL = PW_R1 + PW_R2 + PW_R3 + PW_R4 + PW_R5 + PW_R6; // 6,148,864

__global__ __launch_bounds__(256) void k_prep_w(
    const float* __restrict__ Wih1, const float* __restrict__ Whh1,
    const float* __restrict__ bih1, const float* __restrict__ bhh1,
    const float* __restrict__ Wih2, const float* __restrict__ Whh2,
    const float* __restrict__ bih2, const float* __restrict__ bhh2,
    const float* __restrict__ Wih3, const float* __restrict__ Whh3,
    const float* __restrict__ bih3, const float* __restrict__ bhh3,
    const float* __restrict__ Wfc, unsigned char* __restrict__ ws) {
  long i = (long)blockIdx.x * 256 + threadIdx.x;
  if (i < PW_R1) {
    int n = (int)(i / DP), k = (int)(i % DP);
    int j = n >> 2, g = n & 3;
    float f = (j < HID && k < DIM) ? Wih1[(size_t)(g * HID + j) * DIM + k] : 0.f;
    ((unsigned short*)(ws + OFF_WIH1))[i] = f2bf(f);
    return;
  }
  i -= PW_R1;
  if (i < PW_R2) {
    int L = (int)(i / ((long)GP * KP));
    long r = i % ((long)GP * KP);
    int n = (int)(r / KP), k = (int)(r % KP);
    int j = n >> 2, g = n & 3;
    const float* W = (L == 0) ? Whh1 : (L == 1) ? Whh2 : Whh3;
    float f = (j < HID && k < HID) ? W[(size_t)(g * HID + j) * HID + k] : 0.f;
    ((unsigned short*)(ws + OFF_WHH))[i] = f2bf(f);
    return;
  }
  i -= PW_R2;
  if (i < PW_R3) {
    int L = (int)(i / ((long)GP * KP));
    long r = i % ((long)GP * KP);
    int n = (int)(r / KP), k = (int)(r % KP);
    int j = n >> 2, g = n & 3;
    const float* W = (L == 0) ? Wih2 : Wih3;
    float f = (j < HID && k < HID) ? W[(size_t)(g * HID + j) * HID + k] : 0.f;
    ((unsigned short*)(ws + OFF_WIH23))[i] = f2bf(f);
    return;
  }
  i -= PW_R3;
  if (i < PW_R4) {
    int d = (int)(i / KP), k = (int)(i % KP);
    float f = (d < DIM && k < HID) ? Wfc[(size_t)d * HID + k] : 0.f;
    ((unsigned short*)(ws + OFF_WFC))[i] = f2bf(f);
    return;
  }
  i -= PW_R4;
  if (i < PW_R5) {
    int L = (int)(i / GP);
    int n = (int)(i % GP);
    int j = n >> 2, g = n & 3;
    const float* bi = (L == 0) ? bih1 : (L == 1) ? bih2 : bih3;
    const float* bh = (L == 0) ? bhh1 : (L == 1) ? bhh2 : bhh3;
    float f = (j < HID) ? (bi[g * HID + j] + bh[g * HID + j]) : 0.f;
    ((float*)(ws + OFF_BIAS))[i] = f;
    return;
  }
  i -= PW_R5;
  if (i < PW_R6) ((float*)(ws + OFF_SUMS))[i] = 0.f;
}

// ---------------------------------------------------------------------------
// Generic bf16 NT GEMM (m97 structure): C[M][N] = A[M][K] * B[N][K]^T
// 128x128 tile, BK=64, 4 waves, global_load_lds(16B), 2 barriers / K-step.
// EPI 0: C = acc + bias[col]  (f32 store, ldc)
// EPI 1: FC epilogue: outb = acc + bfc[col] + poly(row,col); row-sum atomics
// ---------------------------------------------------------------------------
template <int EPI>
__global__ __launch_bounds__(256) void k_gemm(
    const unsigned short* __restrict__ A, long ars /*A row stride, elems*/,
    const unsigned short* __restrict__ Bm, int K /*padded, %64==0; also B row stride*/,
    float* __restrict__ C, int ldc,
    const float* __restrict__ bias,
    const float* __restrict__ xsrc, float* __restrict__ sums) {
  __shared__ __align__(16) unsigned char Asm[128 * 64 * 2];
  __shared__ __align__(16) unsigned char Bsm[128 * 64 * 2];
  const int tid = threadIdx.x, lane = tid & 63, w = tid >> 6;
  const int wr = w >> 1, wc = w & 1;
  const int r0 = blockIdx.x * 128;
  const int c0 = blockIdx.y * 128;

  const f32x4 fzero = {0.f, 0.f, 0.f, 0.f};
  f32x4 acc[4][4];
#pragma unroll
  for (int m = 0; m < 4; ++m)
#pragma unroll
    for (int n = 0; n < 4; ++n) acc[m][n] = fzero;

  for (int k0 = 0; k0 < K; k0 += 64) {
#pragma unroll
    for (int i = 0; i < 4; ++i) {
      int base = w * 4096 + i * 1024;
      int beta = base + lane * 16;
      int arow = beta >> 7;          // row within 128-row tile
      int acolb = beta & 127;        // byte within 128B row
      const unsigned short* ga = A + (size_t)(r0 + arow) * ars + k0 + (acolb >> 1);
      gload_lds16(ga, (char*)Asm + base);
      const unsigned short* gb = Bm + (size_t)(c0 + arow) * K + k0 + (acolb >> 1);
      gload_lds16(gb, (char*)Bsm + base);
    }
    __syncthreads();
#pragma unroll
    for (int kk = 0; kk < 2; ++kk) {
      short8 af[4], bfg[4];
#pragma unroll
      for (int m = 0; m < 4; ++m)
        af[m] = *(const short8*)(Asm + (wr * 64 + m * 16 + (lane & 15)) * 128 +
                                 kk * 64 + (lane >> 4) * 16);
#pragma unroll
      for (int n = 0; n < 4; ++n)
        bfg[n] = *(const short8*)(Bsm + (wc * 64 + n * 16 + (lane & 15)) * 128 +
                                  kk * 64 + (lane >> 4) * 16);
#pragma unroll
      for (int m = 0; m < 4; ++m)
#pragma unroll
        for (int n = 0; n < 4; ++n)
          acc[m][n] = __builtin_amdgcn_mfma_f32_16x16x32_bf16(af[m], bfg[n], acc[m][n], 0, 0, 0);
    }
    __syncthreads();
  }

  if (EPI == 0) {
#pragma unroll
    for (int m = 0; m < 4; ++m)
#pragma unroll
      for (int n = 0; n < 4; ++n)
#pragma unroll
        for (int r = 0; r < 4; ++r) {
          int row = r0 + wr * 64 + m * 16 + (lane >> 4) * 4 + r;
          int col = c0 + wc * 64 + n * 16 + (lane & 15);
          C[(size_t)row * ldc + col] = acc[m][n][r] + bias[col];
        }
  } else {
    float s1loc[16], s2loc[16];
#pragma unroll
    for (int i = 0; i < 16; ++i) { s1loc[i] = 0.f; s2loc[i] = 0.f; }
#pragma unroll
    for (int m = 0; m < 4; ++m)
#pragma unroll
      for (int n = 0; n < 4; ++n)
#pragma unroll
        for (int r = 0; r < 4; ++r) {
          int row = r0 + wr * 64 + m * 16 + (lane >> 4) * 4 + r;  // batch b
          int col = c0 + wc * 64 + n * 16 + (lane & 15);
          if (col < DIM) {
            float x13 = xsrc[((size_t)row * 16 + 13) * DIM + col];
            float x14 = xsrc[((size_t)row * 16 + 14) * DIM + col];
            float x15 = xsrc[((size_t)row * 16 + 15) * DIM + col];
            float poly = (x13 + x14 + x15) * (1.f / 3.f) + x15 - x13;
            float v = acc[m][n][r] + bias[col] + poly;
            C[(size_t)row * DIM + col] = v;
            float x0v = xsrc[(size_t)row * 16 * DIM + col];
            s1loc[m * 4 + r] += 1.f - v * v;
            s2loc[m * 4 + r] += x0v - v;
          }
        }
#pragma unroll
    for (int i = 0; i < 16; ++i) {
      float a = s1loc[i], b2 = s2loc[i];
      a += __shfl_xor(a, 1, 64);  b2 += __shfl_xor(b2, 1, 64);
      a += __shfl_xor(a, 2, 64);  b2 += __shfl_xor(b2, 2, 64);
      a += __shfl_xor(a, 4, 64);  b2 += __shfl_xor(b2, 4, 64);
      a += __shfl_xor(a, 8, 64);  b2 += __shfl_xor(b2, 8, 64);
      if ((lane & 15) == 0) {
        int row = r0 + wr * 64 + (i >> 2) * 16 + (lane >> 4) * 4 + (i & 3);
        atomicAdd(&sums[row], a);
        atomicAdd(&sums[BATCH + row], b2);
      }
    }
  }
}

// ---------------------------------------------------------------------------
// Persistent per-batch-chunk LSTM recurrence. 32 blocks x 512 threads.
// Each block owns 16 batch rows for all 16 time steps of one layer.
// gates permuted n'=4j+g; B frags streamed global->VGPR (L2-resident Whh);
// h kept in XOR-swizzled LDS; c kept in registers via quad-lane transpose.
// ---------------------------------------------------------------------------
__global__ __launch_bounds__(512) void k_rec(
    const float* __restrict__ xproj,        // [8192][1280] f32, bias folded
    const unsigned short* __restrict__ Whh, // [1280][320] bf16 permuted
    unsigned short* __restrict__ hhist) {   // [8192][320] bf16
  __shared__ __align__(16) unsigned char hlds[16 * 640];  // [16][320] bf16, swizzled
  const int tid = threadIdx.x, lane = tid & 63, w = tid >> 6;  // w: 0..7
  const int chunk = blockIdx.x;                                 // 0..31

  for (int i = tid; i < 16 * 320; i += 512) ((unsigned short*)hlds)[i] = 0;
  __syncthreads();

  const int mfr = lane & 15;            // A-frag row
  const int q = lane >> 4;
  const int m2 = q * 4 + (lane & 3);    // post-transpose row
  const int aidx = (lane >> 2) & 3;     // unit within tile
  const int nbase = w * 160;

  float c[10];
#pragma unroll
  for (int t = 0; t < 10; ++t) c[t] = 0.f;

  const unsigned short* bptr = Whh + (size_t)(nbase + (lane & 15)) * KP + (lane >> 4) * 8;
  const f32x4 fzero = {0.f, 0.f, 0.f, 0.f};

  for (int ts = 0; ts < TSTEPS; ++ts) {
    // A fragments: h from swizzled LDS
    short8 af[10];
#pragma unroll
    for (int kk = 0; kk < 10; ++kk) {
      int off = (kk * 64 + q * 16) ^ ((mfr & 7) << 4);
      af[kk] = *(const short8*)(hlds + mfr * 640 + off);
    }
    __syncthreads();  // all reads done before anyone rewrites h

    const float* xrow = xproj + ((size_t)(chunk * 16 + m2) * 16 + ts) * GP;

    short8 bfr[2][10];
#pragma unroll
    for (int kk = 0; kk < 10; ++kk)
      bfr[0][kk] = *(const short8*)(bptr + (size_t)kk * 32);

#pragma unroll
    for (int t = 0; t < 10; ++t) {
      float4 xq = *(const float4*)(xrow + nbase + t * 16 + 4 * aidx);
      if (t < 9) {
#pragma unroll
        for (int kk = 0; kk < 10; ++kk)
          bfr[(t + 1) & 1][kk] =
              *(const short8*)(bptr + (size_t)(t + 1) * 16 * KP + (size_t)kk * 32);
      }
      f32x4 a = fzero;
#pragma unroll
      for (int kk = 0; kk < 10; ++kk)
        a = __builtin_amdgcn_mfma_f32_16x16x32_bf16(af[kk], bfr[t & 1][kk], a, 0, 0, 0);

      // 4x4 quad-lane transpose: after, reg r = gate r for row m2
      float v0 = a[0], v1 = a[1], v2 = a[2], v3 = a[3];
      {
        bool hi = lane & 1;
        float s = hi ? v0 : v1; float rr = __shfl_xor(s, 1, 64);
        if (hi) v0 = rr; else v1 = rr;
        s = hi ? v2 : v3; rr = __shfl_xor(s, 1, 64);
        if (hi) v2 = rr; else v3 = rr;
      }
      {
        bool hi = lane & 2;
        float s = hi ? v0 : v2; float rr = __shfl_xor(s, 2, 64);
        if (hi) v0 = rr; else v2 = rr;
        s = hi ? v1 : v3; rr = __shfl_xor(s, 2, 64);
        if (hi) v1 = rr; else v3 = rr;
      }
      float i_ = sigm(v0 + xq.x);
      float f_ = sigm(v1 + xq.y);
      float g_ = tanh_(v2 + xq.z);
      float o_ = sigm(v3 + xq.w);
      float cn = f_ * c[t] + i_ * g_;
      c[t] = cn;
      float hn = o_ * tanh_(cn);
      unsigned short hb = f2bf(hn);
      int u = w * 40 + t * 4 + aidx;
      int off = (2 * u) ^ ((m2 & 7) << 4);
      *(unsigned short*)(hlds + m2 * 640 + off) = hb;
      hhist[((size_t)(chunk * 16 + m2) * 16 + ts) * KP + u] = hb;
    }
    __syncthreads();  // h writes visible before next step's reads
  }
}

// ---------------------------------------------------------------------------
// Final correction: out = outb + (1-outb^2) * s2[b]/s1[b]   (DX cancels)
// ---------------------------------------------------------------------------
__global__ __launch_bounds__(256) void k_final(const float* __restrict__ outb,
                                               const float* __restrict__ sums,
                                               float* __restrict__ out) {
  int idx = blockIdx.x * 256 + threadIdx.x;
  if (idx >= BATCH * DIM) return;
  int b = idx / DIM;
  float v = outb[idx];
  out[idx] = v + (1.f - v * v) * (sums[BATCH + b] / sums[b]);
}

// ---------------------------------------------------------------------------
extern "C" void kernel_launch(void* const* d_in, const int* in_sizes, int n_in,
                              void* d_out, int out_size, void* d_ws, size_t ws_size,
                              hipStream_t stream) {
  if (ws_size < WS_NEED) return;  // workspace too small -> fail loudly

  const float* x    = (const float*)d_in[0];
  const float* Wih1 = (const float*)d_in[1];
  const float* Whh1 = (const float*)d_in[2];
  const float* bih1 = (const float*)d_in[3];
  const float* bhh1 = (const float*)d_in[4];
  const float* Wih2 = (const float*)d_in[5];
  const float* Whh2 = (const float*)d_in[6];
  const float* bih2 = (const float*)d_in[7];
  const float* bhh2 = (const float*)d_in[8];
  const float* Wih3 = (const float*)d_in[9];
  const float* Whh3 = (const float*)d_in[10];
  const float* bih3 = (const float*)d_in[11];
  const float* bhh3 = (const float*)d_in[12];
  const float* Wfc  = (const float*)d_in[13];
  const float* bfc  = (const float*)d_in[14];

  unsigned char* ws = (unsigned char*)d_ws;
  float*          xproj = (float*)(ws + OFF_XPROJ);
  unsigned short* xbf   = (unsigned short*)(ws + OFF_XBF);
  unsigned short* wih1p = (unsigned short*)(ws + OFF_WIH1);
  unsigned short* whh1p = (unsigned short*)(ws + OFF_WHH);
  unsigned short* whh2p = whh1p + (size_t)GP * KP;
  unsigned short* whh3p = whh2p + (size_t)GP * KP;
  unsigned short* wih2p = (unsigned short*)(ws + OFF_WIH23);
  unsigned short* wih3p = wih2p + (size_t)GP * KP;
  unsigned short* wfcp  = (unsigned short*)(ws + OFF_WFC);
  float*          bias1 = (float*)(ws + OFF_BIAS);
  float*          bias2 = bias1 + GP;
  float*          bias3 = bias2 + GP;
  unsigned short* h1    = (unsigned short*)(ws + OFF_H1);
  unsigned short* h2    = (unsigned short*)(ws + OFF_H2);
  unsigned short* h3    = (unsigned short*)(ws + OFF_H3);
  float*          outb  = (float*)(ws + OFF_OUTB);
  float*          sums  = (float*)(ws + OFF_SUMS);

  k_prep_x<<<(BT * (DP / 8) + 255) / 256, 256, 0, stream>>>(x, xbf);
  k_prep_w<<<(int)((PW_TOTAL + 255) / 256), 256, 0, stream>>>(
      Wih1, Whh1, bih1, bhh1, Wih2, Whh2, bih2, bhh2, Wih3, Whh3, bih3, bhh3, Wfc, ws);

  // layer 1
  k_gemm<0><<<dim3(BT / 128, GP / 128), 256, 0, stream>>>(
      xbf, DP, wih1p, DP, xproj, GP, bias1, nullptr, nullptr);
  k_rec<<<32, 512, 0, stream>>>(xproj, whh1p, h1);
  // layer 2
  k_gemm<0><<<dim3(BT / 128, GP / 128), 256, 0, stream>>>(
      h1, KP, wih2p, KP, xproj, GP, bias2, nullptr, nullptr);
  k_rec<<<32, 512, 0, stream>>>(xproj, whh2p, h2);
  // layer 3
  k_gemm<0><<<dim3(BT / 128, GP / 128), 256, 0, stream>>>(
      h2, KP, wih3p, KP, xproj, GP, bias3, nullptr, nullptr);
  k_rec<<<32, 512, 0, stream>>>(xproj, whh3p, h3);

  // FC + poly_bias + row-sum reduction (A rows = h3 at t=15)
  k_gemm<1><<<dim3(BATCH / 128, DP / 128), 256, 0, stream>>>(
      h3 + (size_t)15 * KP, (long)16 * KP, wfcp, KP, outb, DIM, bfc, x, sums);

  k_final<<<(BATCH * DIM + 255) / 256, 256, 0, stream>>>(outb, sums, (float*)d_out);
}

// Round 2
// 861.784 us; speedup vs baseline: 1.6294x; 1.6294x over previous
//
#include <hip/hip_runtime.h>
#include <hip/hip_bf16.h>
#include <stdint.h>
#include <stddef.h>

// ---------------------------------------------------------------------------
// Problem dims
// ---------------------------------------------------------------------------
constexpr int BATCH = 512, TSTEPS = 16, DIM = 2500, HID = 300;
constexpr int BT = BATCH * TSTEPS;   // 8192
constexpr int GP = 1280;             // padded gate count (4*300 -> 1280)
constexpr int KP = 320;              // padded hidden (300 -> 320)
constexpr int DP = 2560;             // padded DIM (2500 -> 2560)

// ---------------------------------------------------------------------------
// Workspace layout (bytes)
// ---------------------------------------------------------------------------
constexpr size_t OFF_XPROJ = 0;                                  // [8192][1280] f32
constexpr size_t SZ_XPROJ  = (size_t)BT * GP * 4;
constexpr size_t OFF_XBF   = OFF_XPROJ + SZ_XPROJ;               // [8192][2560] bf16
constexpr size_t SZ_XBF    = (size_t)BT * DP * 2;
constexpr size_t OFF_WIH1  = OFF_XBF + SZ_XBF;                   // [1280][2560] bf16 (perm)
constexpr size_t SZ_WIH1   = (size_t)GP * DP * 2;
constexpr size_t OFF_WHH   = OFF_WIH1 + SZ_WIH1;                 // 3x [1280][320] bf16 (perm)
constexpr size_t SZ_WHH1   = (size_t)GP * KP * 2;
constexpr size_t OFF_WIH23 = OFF_WHH + 3 * SZ_WHH1;              // 2x [1280][320] bf16 (perm)
constexpr size_t OFF_WFC   = OFF_WIH23 + 2 * SZ_WHH1;            // [2560][320] bf16
constexpr size_t SZ_WFC    = (size_t)DP * KP * 2;
constexpr size_t OFF_BIAS  = OFF_WFC + SZ_WFC;                   // 3x [1280] f32 (perm bih+bhh)
constexpr size_t OFF_H1    = OFF_BIAS + 3 * GP * 4;              // [8192][320] bf16
constexpr size_t SZ_H      = (size_t)BT * KP * 2;
constexpr size_t OFF_H2    = OFF_H1 + SZ_H;
constexpr size_t OFF_H3    = OFF_H2 + SZ_H;
constexpr size_t OFF_OUTB  = OFF_H3 + SZ_H;                      // [512][2500] f32
constexpr size_t OFF_SUMS  = OFF_OUTB + (size_t)BATCH * DIM * 4; // [2][512] f32
constexpr size_t OFF_CNT   = OFF_SUMS + 2 * BATCH * 4;           // [3][32] u32 sync counters
constexpr size_t WS_NEED   = OFF_CNT + 3 * 32 * 4;

typedef __attribute__((ext_vector_type(8))) short short8;
typedef __attribute__((ext_vector_type(4))) float f32x4;

__device__ __forceinline__ unsigned short f2bf(float f) {
  __hip_bfloat16 h = __float2bfloat16(f);
  return *reinterpret_cast<unsigned short*>(&h);
}

__device__ __forceinline__ void gload_lds16(const void* g, void* l) {
  __builtin_amdgcn_global_load_lds(
      (const __attribute__((address_space(1))) unsigned int*)g,
      (__attribute__((address_space(3))) unsigned int*)l,
      16, 0, 0);
}

__device__ __forceinline__ float sigm(float x) { return 1.f / (1.f + __expf(-x)); }
__device__ __forceinline__ float tanh_(float x) {
  x = fminf(fmaxf(x, -30.f), 30.f);
  float e = __expf(2.f * x);
  return (e - 1.f) / (e + 1.f);
}

// ---------------------------------------------------------------------------
// K0a: x f32 -> bf16 padded [8192][2560]
// ---------------------------------------------------------------------------
__global__ __launch_bounds__(256) void k_prep_x(const float* __restrict__ x,
                                                unsigned short* __restrict__ xbf) {
  int idx = blockIdx.x * 256 + threadIdx.x;       // one thread = 8 outputs
  int row = idx / (DP / 8);
  int k8  = (idx % (DP / 8)) * 8;
  if (row >= BT) return;
  short8 v;
  if (k8 + 8 <= DIM) {
    const float* src = x + (size_t)row * DIM + k8;
    float4 f0 = *(const float4*)(src);
    float4 f1 = *(const float4*)(src + 4);
    v[0] = f2bf(f0.x); v[1] = f2bf(f0.y); v[2] = f2bf(f0.z); v[3] = f2bf(f0.w);
    v[4] = f2bf(f1.x); v[5] = f2bf(f1.y); v[6] = f2bf(f1.z); v[7] = f2bf(f1.w);
  } else {
#pragma unroll
    for (int j = 0; j < 8; ++j) {
      int k = k8 + j;
      float f = (k < DIM) ? x[(size_t)row * DIM + k] : 0.f;
      v[j] = f2bf(f);
    }
  }
  *reinterpret_cast<short8*>(xbf + (size_t)row * DP + k8) = v;
}

// ---------------------------------------------------------------------------
// K0b: all weights -> bf16, gate-permuted (n' = 4*j + g), padded; bias sums;
// zero sums + sync counters
// ---------------------------------------------------------------------------
constexpr long PW_R1 = (long)GP * DP;          // Wih1p
constexpr long PW_R2 = 3L * GP * KP;           // Whh1..3
constexpr long PW_R3 = 2L * GP * KP;           // Wih2,3
constexpr long PW_R4 = (long)DP * KP;          // Wfc
constexpr long PW_R5 = 3L * GP;                // biases
constexpr long PW_R6 = 2L * BATCH + 3 * 32;    // sums + counters zero
constexpr long PW_TOTAL = PW_R1 + PW_R2 + PW_R3 + PW_R4 + PW_R5 + PW_R6;

__global__ __launch_bounds__(256) void k_prep_w(
    const float* __restrict__ Wih1, const float* __restrict__ Whh1,
    const float* __restrict__ bih1, const float* __restrict__ bhh1,
    const float* __restrict__ Wih2, const float* __restrict__ Whh2,
    const float* __restrict__ bih2, const float* __restrict__ bhh2,
    const float* __restrict__ Wih3, const float* __restrict__ Whh3,
    const float* __restrict__ bih3, const float* __restrict__ bhh3,
    const float* __restrict__ Wfc, unsigned char* __restrict__ ws) {
  long i = (long)blockIdx.x * 256 + threadIdx.x;
  if (i < PW_R1) {
    int n = (int)(i / DP), k = (int)(i % DP);
    int j = n >> 2, g = n & 3;
    float f = (j < HID && k < DIM) ? Wih1[(size_t)(g * HID + j) * DIM + k] : 0.f;
    ((unsigned short*)(ws + OFF_WIH1))[i] = f2bf(f);
    return;
  }
  i -= PW_R1;
  if (i < PW_R2) {
    int L = (int)(i / ((long)GP * KP));
    long r = i % ((long)GP * KP);
    int n = (int)(r / KP), k = (int)(r % KP);
    int j = n >> 2, g = n & 3;
    const float* W = (L == 0) ? Whh1 : (L == 1) ? Whh2 : Whh3;
    float f = (j < HID && k < HID) ? W[(size_t)(g * HID + j) * HID + k] : 0.f;
    ((unsigned short*)(ws + OFF_WHH))[i] = f2bf(f);
    return;
  }
  i -= PW_R2;
  if (i < PW_R3) {
    int L = (int)(i / ((long)GP * KP));
    long r = i % ((long)GP * KP);
    int n = (int)(r / KP), k = (int)(r % KP);
    int j = n >> 2, g = n & 3;
    const float* W = (L == 0) ? Wih2 : Wih3;
    float f = (j < HID && k < HID) ? W[(size_t)(g * HID + j) * HID + k] : 0.f;
    ((unsigned short*)(ws + OFF_WIH23))[i] = f2bf(f);
    return;
  }
  i -= PW_R3;
  if (i < PW_R4) {
    int d = (int)(i / KP), k = (int)(i % KP);
    float f = (d < DIM && k < HID) ? Wfc[(size_t)d * HID + k] : 0.f;
    ((unsigned short*)(ws + OFF_WFC))[i] = f2bf(f);
    return;
  }
  i -= PW_R4;
  if (i < PW_R5) {
    int L = (int)(i / GP);
    int n = (int)(i % GP);
    int j = n >> 2, g = n & 3;
    const float* bi = (L == 0) ? bih1 : (L == 1) ? bih2 : bih3;
    const float* bh = (L == 0) ? bhh1 : (L == 1) ? bhh2 : bhh3;
    float f = (j < HID) ? (bi[g * HID + j] + bh[g * HID + j]) : 0.f;
    ((float*)(ws + OFF_BIAS))[i] = f;
    return;
  }
  i -= PW_R5;
  if (i < PW_R6) ((unsigned int*)(ws + OFF_SUMS))[i] = 0u;  // sums + counters
}

// ---------------------------------------------------------------------------
// Generic bf16 NT GEMM (m97 structure): C[M][N] = A[M][K] * B[N][K]^T
// ---------------------------------------------------------------------------
template <int EPI>
__global__ __launch_bounds__(256) void k_gemm(
    const unsigned short* __restrict__ A, long ars,
    const unsigned short* __restrict__ Bm, int K,
    float* __restrict__ C, int ldc,
    const float* __restrict__ bias,
    const float* __restrict__ xsrc, float* __restrict__ sums) {
  __shared__ __align__(16) unsigned char Asm[128 * 64 * 2];
  __shared__ __align__(16) unsigned char Bsm[128 * 64 * 2];
  const int tid = threadIdx.x, lane = tid & 63, w = tid >> 6;
  const int wr = w >> 1, wc = w & 1;
  const int r0 = blockIdx.x * 128;
  const int c0 = blockIdx.y * 128;

  const f32x4 fzero = {0.f, 0.f, 0.f, 0.f};
  f32x4 acc[4][4];
#pragma unroll
  for (int m = 0; m < 4; ++m)
#pragma unroll
    for (int n = 0; n < 4; ++n) acc[m][n] = fzero;

  for (int k0 = 0; k0 < K; k0 += 64) {
#pragma unroll
    for (int i = 0; i < 4; ++i) {
      int base = w * 4096 + i * 1024;
      int beta = base + lane * 16;
      int arow = beta >> 7;
      int acolb = beta & 127;
      const unsigned short* ga = A + (size_t)(r0 + arow) * ars + k0 + (acolb >> 1);
      gload_lds16(ga, (char*)Asm + base);
      const unsigned short* gb = Bm + (size_t)(c0 + arow) * K + k0 + (acolb >> 1);
      gload_lds16(gb, (char*)Bsm + base);
    }
    __syncthreads();
#pragma unroll
    for (int kk = 0; kk < 2; ++kk) {
      short8 af[4], bfg[4];
#pragma unroll
      for (int m = 0; m < 4; ++m)
        af[m] = *(const short8*)(Asm + (wr * 64 + m * 16 + (lane & 15)) * 128 +
                                 kk * 64 + (lane >> 4) * 16);
#pragma unroll
      for (int n = 0; n < 4; ++n)
        bfg[n] = *(const short8*)(Bsm + (wc * 64 + n * 16 + (lane & 15)) * 128 +
                                  kk * 64 + (lane >> 4) * 16);
#pragma unroll
      for (int m = 0; m < 4; ++m)
#pragma unroll
        for (int n = 0; n < 4; ++n)
          acc[m][n] = __builtin_amdgcn_mfma_f32_16x16x32_bf16(af[m], bfg[n], acc[m][n], 0, 0, 0);
    }
    __syncthreads();
  }

  if (EPI == 0) {
#pragma unroll
    for (int m = 0; m < 4; ++m)
#pragma unroll
      for (int n = 0; n < 4; ++n)
#pragma unroll
        for (int r = 0; r < 4; ++r) {
          int row = r0 + wr * 64 + m * 16 + (lane >> 4) * 4 + r;
          int col = c0 + wc * 64 + n * 16 + (lane & 15);
          C[(size_t)row * ldc + col] = acc[m][n][r] + bias[col];
        }
  } else {
    float s1loc[16], s2loc[16];
#pragma unroll
    for (int i = 0; i < 16; ++i) { s1loc[i] = 0.f; s2loc[i] = 0.f; }
#pragma unroll
    for (int m = 0; m < 4; ++m)
#pragma unroll
      for (int n = 0; n < 4; ++n)
#pragma unroll
        for (int r = 0; r < 4; ++r) {
          int row = r0 + wr * 64 + m * 16 + (lane >> 4) * 4 + r;
          int col = c0 + wc * 64 + n * 16 + (lane & 15);
          if (col < DIM) {
            float x13 = xsrc[((size_t)row * 16 + 13) * DIM + col];
            float x14 = xsrc[((size_t)row * 16 + 14) * DIM + col];
            float x15 = xsrc[((size_t)row * 16 + 15) * DIM + col];
            float poly = (x13 + x14 + x15) * (1.f / 3.f) + x15 - x13;
            float v = acc[m][n][r] + bias[col] + poly;
            C[(size_t)row * DIM + col] = v;
            float x0v = xsrc[(size_t)row * 16 * DIM + col];
            s1loc[m * 4 + r] += 1.f - v * v;
            s2loc[m * 4 + r] += x0v - v;
          }
        }
#pragma unroll
    for (int i = 0; i < 16; ++i) {
      float a = s1loc[i], b2 = s2loc[i];
      a += __shfl_xor(a, 1, 64);  b2 += __shfl_xor(b2, 1, 64);
      a += __shfl_xor(a, 2, 64);  b2 += __shfl_xor(b2, 2, 64);
      a += __shfl_xor(a, 4, 64);  b2 += __shfl_xor(b2, 4, 64);
      a += __shfl_xor(a, 8, 64);  b2 += __shfl_xor(b2, 8, 64);
      if ((lane & 15) == 0) {
        int row = r0 + wr * 64 + (i >> 2) * 16 + (lane >> 4) * 4 + (i & 3);
        atomicAdd(&sums[row], a);
        atomicAdd(&sums[BATCH + row], b2);
      }
    }
  }
}

// ---------------------------------------------------------------------------
// LSTM recurrence v2: gate-split across 5 blocks per batch-chunk.
// Grid = 160 blocks (s*32 + c so the 5 group-mates share an XCD), 512 thr.
// Each wave owns 32 gates; its Whh slab lives in REGISTERS for all 16 steps
// (zero per-step weight traffic). h exchanged via hhist + agent-scope
// release/acquire counter sync (cross-XCD safe). t=0 skips sync (h=0).
// ---------------------------------------------------------------------------
__global__ __launch_bounds__(512, 2) void k_rec(
    const float* __restrict__ xproj,        // [8192][1280] f32, bias folded
    const unsigned short* __restrict__ Whh, // [1280][320] bf16 permuted
    unsigned short* __restrict__ hhist,     // [8192][320] bf16
    unsigned int* __restrict__ cnt) {       // [32] zeroed
  const int tid = threadIdx.x, lane = tid & 63, w = tid >> 6;  // 8 waves
  const int c = blockIdx.x & 31;        // batch chunk (16 rows)
  const int s = blockIdx.x >> 5;        // gate slab 0..4
  const int gbase = s * 256 + w * 32;   // first gate owned by this wave

  // --- persistent B fragments: 32 gates x 320 K in VGPRs (80 regs) ---
  short8 b[2][10];
#pragma unroll
  for (int nt = 0; nt < 2; ++nt)
#pragma unroll
    for (int kk = 0; kk < 10; ++kk)
      b[nt][kk] = *(const short8*)(Whh +
          (size_t)(gbase + nt * 16 + (lane & 15)) * KP + kk * 32 + (lane >> 4) * 8);

  const int q = lane >> 4;
  const int m2 = q * 4 + (lane & 3);     // post-transpose batch row
  const int aidx = (lane >> 2) & 3;      // unit within 16-gate tile
  const int ubase = s * 64 + w * 8;      // first h-unit owned by this wave
  const f32x4 fzero = {0.f, 0.f, 0.f, 0.f};

  float cst[2] = {0.f, 0.f};
  const size_t xrowb = (size_t)(c * 16 + m2) * 16;         // xproj/hhist row (m2)
  const size_t arowb = (size_t)(c * 16 + (lane & 15)) * 16; // hhist row (A-frag)

  for (int t = 0; t < TSTEPS; ++t) {
    // xq loads are sync-independent; issue before anything else
    float4 xq[2];
#pragma unroll
    for (int nt = 0; nt < 2; ++nt)
      xq[nt] = *(const float4*)(xproj + (xrowb + t) * GP + gbase + nt * 16 + 4 * aidx);

    f32x4 acc[2] = {fzero, fzero};
    if (t > 0) {
      short8 af[10];
#pragma unroll
      for (int kk = 0; kk < 10; ++kk)
        af[kk] = *(const short8*)(hhist + (arowb + (t - 1)) * KP + kk * 32 + q * 8);
#pragma unroll
      for (int nt = 0; nt < 2; ++nt) {
        f32x4 a0 = fzero, a1 = fzero;
#pragma unroll
        for (int kk = 0; kk < 5; ++kk) {
          a0 = __builtin_amdgcn_mfma_f32_16x16x32_bf16(af[2 * kk], b[nt][2 * kk], a0, 0, 0, 0);
          a1 = __builtin_amdgcn_mfma_f32_16x16x32_bf16(af[2 * kk + 1], b[nt][2 * kk + 1], a1, 0, 0, 0);
        }
        acc[nt] = a0 + a1;
      }
    }

#pragma unroll
    for (int nt = 0; nt < 2; ++nt) {
      float v0 = acc[nt][0], v1 = acc[nt][1], v2 = acc[nt][2], v3 = acc[nt][3];
      {  // 4x4 quad-lane transpose (lanes within quad swap regs<->cols)
        bool hi = lane & 1;
        float sS = hi ? v0 : v1; float rr = __shfl_xor(sS, 1, 64);
        if (hi) v0 = rr; else v1 = rr;
        sS = hi ? v2 : v3; rr = __shfl_xor(sS, 1, 64);
        if (hi) v2 = rr; else v3 = rr;
      }
      {
        bool hi = lane & 2;
        float sS = hi ? v0 : v2; float rr = __shfl_xor(sS, 2, 64);
        if (hi) v0 = rr; else v2 = rr;
        sS = hi ? v1 : v3; rr = __shfl_xor(sS, 2, 64);
        if (hi) v1 = rr; else v3 = rr;
      }
      float i_ = sigm(v0 + xq[nt].x);
      float f_ = sigm(v1 + xq[nt].y);
      float g_ = tanh_(v2 + xq[nt].z);
      float o_ = sigm(v3 + xq[nt].w);
      float cn = f_ * cst[nt] + i_ * g_;
      cst[nt] = cn;
      float hn = o_ * tanh_(cn);
      hhist[(xrowb + t) * KP + ubase + nt * 4 + aidx] = f2bf(hn);
    }

    if (t < TSTEPS - 1) {
      __syncthreads();  // drains all waves' h stores (vmcnt 0 before barrier)
      if (tid == 0) {
        __hip_atomic_fetch_add(cnt + c, 1u, __ATOMIC_RELEASE, __HIP_MEMORY_SCOPE_AGENT);
        unsigned tgt = 5u * (unsigned)(t + 1);
        while (__hip_atomic_load(cnt + c, __ATOMIC_ACQUIRE, __HIP_MEMORY_SCOPE_AGENT) < tgt) {}
      }
      __syncthreads();
    }
  }
}

// ---------------------------------------------------------------------------
// Final correction: out = outb + (1-outb^2) * s2[b]/s1[b]   (DX cancels)
// ---------------------------------------------------------------------------
__global__ __launch_bounds__(256) void k_final(const float* __restrict__ outb,
                                               const float* __restrict__ sums,
                                               float* __restrict__ out) {
  int idx = blockIdx.x * 256 + threadIdx.x;
  if (idx >= BATCH * DIM) return;
  int b = idx / DIM;
  float v = outb[idx];
  out[idx] = v + (1.f - v * v) * (sums[BATCH + b] / sums[b]);
}

// ---------------------------------------------------------------------------
extern "C" void kernel_launch(void* const* d_in, const int* in_sizes, int n_in,
                              void* d_out, int out_size, void* d_ws, size_t ws_size,
                              hipStream_t stream) {
  if (ws_size < WS_NEED) return;

  const float* x    = (const float*)d_in[0];
  const float* Wih1 = (const float*)d_in[1];
  const float* Whh1 = (const float*)d_in[2];
  const float* bih1 = (const float*)d_in[3];
  const float* bhh1 = (const float*)d_in[4];
  const float* Wih2 = (const float*)d_in[5];
  const float* Whh2 = (const float*)d_in[6];
  const float* bih2 = (const float*)d_in[7];
  const float* bhh2 = (const float*)d_in[8];
  const float* Wih3 = (const float*)d_in[9];
  const float* Whh3 = (const float*)d_in[10];
  const float* bih3 = (const float*)d_in[11];
  const float* bhh3 = (const float*)d_in[12];
  const float* Wfc  = (const float*)d_in[13];
  const float* bfc  = (const float*)d_in[14];

  unsigned char* ws = (unsigned char*)d_ws;
  float*          xproj = (float*)(ws + OFF_XPROJ);
  unsigned short* xbf   = (unsigned short*)(ws + OFF_XBF);
  unsigned short* wih1p = (unsigned short*)(ws + OFF_WIH1);
  unsigned short* whh1p = (unsigned short*)(ws + OFF_WHH);
  unsigned short* whh2p = whh1p + (size_t)GP * KP;
  unsigned short* whh3p = whh2p + (size_t)GP * KP;
  unsigned short* wih2p = (unsigned short*)(ws + OFF_WIH23);
  unsigned short* wih3p = wih2p + (size_t)GP * KP;
  unsigned short* wfcp  = (unsigned short*)(ws + OFF_WFC);
  float*          bias1 = (float*)(ws + OFF_BIAS);
  float*          bias2 = bias1 + GP;
  float*          bias3 = bias2 + GP;
  unsigned short* h1    = (unsigned short*)(ws + OFF_H1);
  unsigned short* h2    = (unsigned short*)(ws + OFF_H2);
  unsigned short* h3    = (unsigned short*)(ws + OFF_H3);
  float*          outb  = (float*)(ws + OFF_OUTB);
  float*          sums  = (float*)(ws + OFF_SUMS);
  unsigned int*   cnt   = (unsigned int*)(ws + OFF_CNT);

  k_prep_x<<<(BT * (DP / 8) + 255) / 256, 256, 0, stream>>>(x, xbf);
  k_prep_w<<<(int)((PW_TOTAL + 255) / 256), 256, 0, stream>>>(
      Wih1, Whh1, bih1, bhh1, Wih2, Whh2, bih2, bhh2, Wih3, Whh3, bih3, bhh3, Wfc, ws);

  // layer 1
  k_gemm<0><<<dim3(BT / 128, GP / 128), 256, 0, stream>>>(
      xbf, DP, wih1p, DP, xproj, GP, bias1, nullptr, nullptr);
  k_rec<<<160, 512, 0, stream>>>(xproj, whh1p, h1, cnt + 0 * 32);
  // layer 2
  k_gemm<0><<<dim3(BT / 128, GP / 128), 256, 0, stream>>>(
      h1, KP, wih2p, KP, xproj, GP, bias2, nullptr, nullptr);
  k_rec<<<160, 512, 0, stream>>>(xproj, whh2p, h2, cnt + 1 * 32);
  // layer 3
  k_gemm<0><<<dim3(BT / 128, GP / 128), 256, 0, stream>>>(
      h2, KP, wih3p, KP, xproj, GP, bias3, nullptr, nullptr);
  k_rec<<<160, 512, 0, stream>>>(xproj, whh3p, h3, cnt + 2 * 32);

  // FC + poly_bias + row-sum reduction (A rows = h3 at t=15)
  k_gemm<1><<<dim3(BATCH / 128, DP / 128), 256, 0, stream>>>(
      h3 + (size_t)15 * KP, (long)16 * KP, wfcp, KP, outb, DIM, bfc, x, sums);

  k_final<<<(BATCH * DIM + 255) / 256, 256, 0, stream>>>(outb, sums, (float*)d_out);
}

// Round 3
// 795.560 us; speedup vs baseline: 1.7650x; 1.0832x over previous
//
#include <hip/hip_runtime.h>
#include <hip/hip_bf16.h>
#include <stdint.h>
#include <stddef.h>

// ---------------------------------------------------------------------------
// Problem dims
// ---------------------------------------------------------------------------
constexpr int BATCH = 512, TSTEPS = 16, DIM = 2500, HID = 300;
constexpr int BT = BATCH * TSTEPS;   // 8192
constexpr int GP = 1280;             // padded gate count (4*300 -> 1280)
constexpr int KP = 320;              // padded hidden (300 -> 320)
constexpr int DP = 2560;             // padded DIM (2500 -> 2560)

// ---------------------------------------------------------------------------
// Workspace layout (bytes)
// ---------------------------------------------------------------------------
constexpr size_t OFF_XPROJ = 0;                                  // [8192][1280] f32
constexpr size_t SZ_XPROJ  = (size_t)BT * GP * 4;
constexpr size_t OFF_XBF   = OFF_XPROJ + SZ_XPROJ;               // [8192][2560] bf16
constexpr size_t SZ_XBF    = (size_t)BT * DP * 2;
constexpr size_t OFF_WIH1  = OFF_XBF + SZ_XBF;                   // [1280][2560] bf16 (perm)
constexpr size_t SZ_WIH1   = (size_t)GP * DP * 2;
constexpr size_t OFF_WHH   = OFF_WIH1 + SZ_WIH1;                 // 3x [1280][320] bf16 (perm)
constexpr size_t SZ_WHH1   = (size_t)GP * KP * 2;
constexpr size_t OFF_WIH23 = OFF_WHH + 3 * SZ_WHH1;              // 2x [1280][320] bf16 (perm)
constexpr size_t OFF_WFC   = OFF_WIH23 + 2 * SZ_WHH1;            // [2560][320] bf16
constexpr size_t SZ_WFC    = (size_t)DP * KP * 2;
constexpr size_t OFF_BIAS  = OFF_WFC + SZ_WFC;                   // 3x [1280] f32 (perm bih+bhh)
constexpr size_t OFF_H1    = OFF_BIAS + 3 * GP * 4;              // [8192][320] bf16
constexpr size_t SZ_H      = (size_t)BT * KP * 2;
constexpr size_t OFF_H2    = OFF_H1 + SZ_H;
constexpr size_t OFF_H3    = OFF_H2 + SZ_H;
constexpr size_t OFF_OUTB  = OFF_H3 + SZ_H;                      // [512][2500] f32
constexpr size_t OFF_SUMS  = OFF_OUTB + (size_t)BATCH * DIM * 4; // [2][512] f32
constexpr size_t OFF_CNT   = OFF_SUMS + 2 * BATCH * 4;           // [3][32] u32 sync counters
constexpr size_t WS_NEED   = OFF_CNT + 3 * 32 * 4;

typedef __attribute__((ext_vector_type(8))) short short8;
typedef __attribute__((ext_vector_type(4))) float f32x4;

__device__ __forceinline__ unsigned short f2bf(float f) {
  __hip_bfloat16 h = __float2bfloat16(f);
  return *reinterpret_cast<unsigned short*>(&h);
}

__device__ __forceinline__ void gload_lds16(const void* g, void* l) {
  __builtin_amdgcn_global_load_lds(
      (const __attribute__((address_space(1))) unsigned int*)g,
      (__attribute__((address_space(3))) unsigned int*)l,
      16, 0, 0);
}

__device__ __forceinline__ float sigm(float x) { return 1.f / (1.f + __expf(-x)); }
__device__ __forceinline__ float tanh_(float x) {
  x = fminf(fmaxf(x, -30.f), 30.f);
  float e = __expf(2.f * x);
  return (e - 1.f) / (e + 1.f);
}

// ---------------------------------------------------------------------------
// K0a: x f32 -> bf16 padded [8192][2560]
// ---------------------------------------------------------------------------
__global__ __launch_bounds__(256) void k_prep_x(const float* __restrict__ x,
                                                unsigned short* __restrict__ xbf) {
  int idx = blockIdx.x * 256 + threadIdx.x;       // one thread = 8 outputs
  int row = idx / (DP / 8);
  int k8  = (idx % (DP / 8)) * 8;
  if (row >= BT) return;
  short8 v;
  if (k8 + 8 <= DIM) {
    const float* src = x + (size_t)row * DIM + k8;
    float4 f0 = *(const float4*)(src);
    float4 f1 = *(const float4*)(src + 4);
    v[0] = f2bf(f0.x); v[1] = f2bf(f0.y); v[2] = f2bf(f0.z); v[3] = f2bf(f0.w);
    v[4] = f2bf(f1.x); v[5] = f2bf(f1.y); v[6] = f2bf(f1.z); v[7] = f2bf(f1.w);
  } else {
#pragma unroll
    for (int j = 0; j < 8; ++j) {
      int k = k8 + j;
      float f = (k < DIM) ? x[(size_t)row * DIM + k] : 0.f;
      v[j] = f2bf(f);
    }
  }
  *reinterpret_cast<short8*>(xbf + (size_t)row * DP + k8) = v;
}

// ---------------------------------------------------------------------------
// K0b: all weights -> bf16, gate-permuted (n' = 4*j + g), padded; bias sums;
// zero sums + sync counters
// ---------------------------------------------------------------------------
constexpr long PW_R1 = (long)GP * DP;          // Wih1p
constexpr long PW_R2 = 3L * GP * KP;           // Whh1..3
constexpr long PW_R3 = 2L * GP * KP;           // Wih2,3
constexpr long PW_R4 = (long)DP * KP;          // Wfc
constexpr long PW_R5 = 3L * GP;                // biases
constexpr long PW_R6 = 2L * BATCH + 3 * 32;    // sums + counters zero
constexpr long PW_TOTAL = PW_R1 + PW_R2 + PW_R3 + PW_R4 + PW_R5 + PW_R6;

__global__ __launch_bounds__(256) void k_prep_w(
    const float* __restrict__ Wih1, const float* __restrict__ Whh1,
    const float* __restrict__ bih1, const float* __restrict__ bhh1,
    const float* __restrict__ Wih2, const float* __restrict__ Whh2,
    const float* __restrict__ bih2, const float* __restrict__ bhh2,
    const float* __restrict__ Wih3, const float* __restrict__ Whh3,
    const float* __restrict__ bih3, const float* __restrict__ bhh3,
    const float* __restrict__ Wfc, unsigned char* __restrict__ ws) {
  long i = (long)blockIdx.x * 256 + threadIdx.x;
  if (i < PW_R1) {
    int n = (int)(i / DP), k = (int)(i % DP);
    int j = n >> 2, g = n & 3;
    float f = (j < HID && k < DIM) ? Wih1[(size_t)(g * HID + j) * DIM + k] : 0.f;
    ((unsigned short*)(ws + OFF_WIH1))[i] = f2bf(f);
    return;
  }
  i -= PW_R1;
  if (i < PW_R2) {
    int L = (int)(i / ((long)GP * KP));
    long r = i % ((long)GP * KP);
    int n = (int)(r / KP), k = (int)(r % KP);
    int j = n >> 2, g = n & 3;
    const float* W = (L == 0) ? Whh1 : (L == 1) ? Whh2 : Whh3;
    float f = (j < HID && k < HID) ? W[(size_t)(g * HID + j) * HID + k] : 0.f;
    ((unsigned short*)(ws + OFF_WHH))[i] = f2bf(f);
    return;
  }
  i -= PW_R2;
  if (i < PW_R3) {
    int L = (int)(i / ((long)GP * KP));
    long r = i % ((long)GP * KP);
    int n = (int)(r / KP), k = (int)(r % KP);
    int j = n >> 2, g = n & 3;
    const float* W = (L == 0) ? Wih2 : Wih3;
    float f = (j < HID && k < HID) ? W[(size_t)(g * HID + j) * HID + k] : 0.f;
    ((unsigned short*)(ws + OFF_WIH23))[i] = f2bf(f);
    return;
  }
  i -= PW_R3;
  if (i < PW_R4) {
    int d = (int)(i / KP), k = (int)(i % KP);
    float f = (d < DIM && k < HID) ? Wfc[(size_t)d * HID + k] : 0.f;
    ((unsigned short*)(ws + OFF_WFC))[i] = f2bf(f);
    return;
  }
  i -= PW_R4;
  if (i < PW_R5) {
    int L = (int)(i / GP);
    int n = (int)(i % GP);
    int j = n >> 2, g = n & 3;
    const float* bi = (L == 0) ? bih1 : (L == 1) ? bih2 : bih3;
    const float* bh = (L == 0) ? bhh1 : (L == 1) ? bhh2 : bhh3;
    float f = (j < HID) ? (bi[g * HID + j] + bh[g * HID + j]) : 0.f;
    ((float*)(ws + OFF_BIAS))[i] = f;
    return;
  }
  i -= PW_R5;
  if (i < PW_R6) ((unsigned int*)(ws + OFF_SUMS))[i] = 0u;  // sums + counters
}

// ---------------------------------------------------------------------------
// Generic bf16 NT GEMM (m97 structure): C[M][N] = A[M][K] * B[N][K]^T
// ---------------------------------------------------------------------------
template <int EPI>
__global__ __launch_bounds__(256) void k_gemm(
    const unsigned short* __restrict__ A, long ars,
    const unsigned short* __restrict__ Bm, int K,
    float* __restrict__ C, int ldc,
    const float* __restrict__ bias,
    const float* __restrict__ xsrc, float* __restrict__ sums) {
  __shared__ __align__(16) unsigned char Asm[128 * 64 * 2];
  __shared__ __align__(16) unsigned char Bsm[128 * 64 * 2];
  const int tid = threadIdx.x, lane = tid & 63, w = tid >> 6;
  const int wr = w >> 1, wc = w & 1;
  const int r0 = blockIdx.x * 128;
  const int c0 = blockIdx.y * 128;

  const f32x4 fzero = {0.f, 0.f, 0.f, 0.f};
  f32x4 acc[4][4];
#pragma unroll
  for (int m = 0; m < 4; ++m)
#pragma unroll
    for (int n = 0; n < 4; ++n) acc[m][n] = fzero;

  for (int k0 = 0; k0 < K; k0 += 64) {
#pragma unroll
    for (int i = 0; i < 4; ++i) {
      int base = w * 4096 + i * 1024;
      int beta = base + lane * 16;
      int arow = beta >> 7;
      int acolb = beta & 127;
      const unsigned short* ga = A + (size_t)(r0 + arow) * ars + k0 + (acolb >> 1);
      gload_lds16(ga, (char*)Asm + base);
      const unsigned short* gb = Bm + (size_t)(c0 + arow) * K + k0 + (acolb >> 1);
      gload_lds16(gb, (char*)Bsm + base);
    }
    __syncthreads();
#pragma unroll
    for (int kk = 0; kk < 2; ++kk) {
      short8 af[4], bfg[4];
#pragma unroll
      for (int m = 0; m < 4; ++m)
        af[m] = *(const short8*)(Asm + (wr * 64 + m * 16 + (lane & 15)) * 128 +
                                 kk * 64 + (lane >> 4) * 16);
#pragma unroll
      for (int n = 0; n < 4; ++n)
        bfg[n] = *(const short8*)(Bsm + (wc * 64 + n * 16 + (lane & 15)) * 128 +
                                  kk * 64 + (lane >> 4) * 16);
#pragma unroll
      for (int m = 0; m < 4; ++m)
#pragma unroll
        for (int n = 0; n < 4; ++n)
          acc[m][n] = __builtin_amdgcn_mfma_f32_16x16x32_bf16(af[m], bfg[n], acc[m][n], 0, 0, 0);
    }
    __syncthreads();
  }

  if (EPI == 0) {
#pragma unroll
    for (int m = 0; m < 4; ++m)
#pragma unroll
      for (int n = 0; n < 4; ++n)
#pragma unroll
        for (int r = 0; r < 4; ++r) {
          int row = r0 + wr * 64 + m * 16 + (lane >> 4) * 4 + r;
          int col = c0 + wc * 64 + n * 16 + (lane & 15);
          C[(size_t)row * ldc + col] = acc[m][n][r] + bias[col];
        }
  } else {
    float s1loc[16], s2loc[16];
#pragma unroll
    for (int i = 0; i < 16; ++i) { s1loc[i] = 0.f; s2loc[i] = 0.f; }
#pragma unroll
    for (int m = 0; m < 4; ++m)
#pragma unroll
      for (int n = 0; n < 4; ++n)
#pragma unroll
        for (int r = 0; r < 4; ++r) {
          int row = r0 + wr * 64 + m * 16 + (lane >> 4) * 4 + r;
          int col = c0 + wc * 64 + n * 16 + (lane & 15);
          if (col < DIM) {
            float x13 = xsrc[((size_t)row * 16 + 13) * DIM + col];
            float x14 = xsrc[((size_t)row * 16 + 14) * DIM + col];
            float x15 = xsrc[((size_t)row * 16 + 15) * DIM + col];
            float poly = (x13 + x14 + x15) * (1.f / 3.f) + x15 - x13;
            float v = acc[m][n][r] + bias[col] + poly;
            C[(size_t)row * DIM + col] = v;
            float x0v = xsrc[(size_t)row * 16 * DIM + col];
            s1loc[m * 4 + r] += 1.f - v * v;
            s2loc[m * 4 + r] += x0v - v;
          }
        }
#pragma unroll
    for (int i = 0; i < 16; ++i) {
      float a = s1loc[i], b2 = s2loc[i];
      a += __shfl_xor(a, 1, 64);  b2 += __shfl_xor(b2, 1, 64);
      a += __shfl_xor(a, 2, 64);  b2 += __shfl_xor(b2, 2, 64);
      a += __shfl_xor(a, 4, 64);  b2 += __shfl_xor(b2, 4, 64);
      a += __shfl_xor(a, 8, 64);  b2 += __shfl_xor(b2, 8, 64);
      if ((lane & 15) == 0) {
        int row = r0 + wr * 64 + (i >> 2) * 16 + (lane >> 4) * 4 + (i & 3);
        atomicAdd(&sums[row], a);
        atomicAdd(&sums[BATCH + row], b2);
      }
    }
  }
}

// ---------------------------------------------------------------------------
// LSTM recurrence v3: gate-split across 5 blocks per batch-chunk.
// Whh slab PINNED in VGPRs via empty asm (compiler may not re-materialize);
// relaxed-poll + single acquire fence per step; xq prefetched past release.
// ---------------------------------------------------------------------------
__global__ __launch_bounds__(512, 2) void k_rec(
    const float* __restrict__ xproj,        // [8192][1280] f32, bias folded
    const unsigned short* __restrict__ Whh, // [1280][320] bf16 permuted
    unsigned short* __restrict__ hhist,     // [8192][320] bf16
    unsigned int* __restrict__ cnt) {       // [32] zeroed
  const int tid = threadIdx.x, lane = tid & 63, w = tid >> 6;  // 8 waves
  const int c = blockIdx.x & 31;        // batch chunk (16 rows)
  const int s = blockIdx.x >> 5;        // gate slab 0..4
  const int gbase = s * 256 + w * 32;   // first gate owned by this wave

  // --- persistent B fragments: 32 gates x 320 K in VGPRs (80 regs) ---
  short8 b[2][10];
#pragma unroll
  for (int nt = 0; nt < 2; ++nt)
#pragma unroll
    for (int kk = 0; kk < 10; ++kk)
      b[nt][kk] = *(const short8*)(Whh +
          (size_t)(gbase + nt * 16 + (lane & 15)) * KP + kk * 32 + (lane >> 4) * 8);

  const int q = lane >> 4;
  const int m2 = q * 4 + (lane & 3);     // post-transpose batch row
  const int aidx = (lane >> 2) & 3;      // unit within 16-gate tile
  const int ubase = s * 64 + w * 8;      // first h-unit owned by this wave
  const f32x4 fzero = {0.f, 0.f, 0.f, 0.f};

  float cst[2] = {0.f, 0.f};
  const size_t xrowb = (size_t)(c * 16 + m2) * 16;          // xproj/hhist row (m2)
  const size_t arowb = (size_t)(c * 16 + (lane & 15)) * 16; // hhist row (A-frag)

  float4 xq[2];
#pragma unroll
  for (int nt = 0; nt < 2; ++nt)
    xq[nt] = *(const float4*)(xproj + xrowb * GP + gbase + nt * 16 + 4 * aidx);

  for (int t = 0; t < TSTEPS; ++t) {
    // Force the 20 B fragments to stay register-resident across the loop:
    // the empty asm "redefines" them each iteration, so the initial global
    // loads cannot be sunk/rematerialized into the loop body.
    asm volatile("" :
        "+v"(b[0][0]), "+v"(b[0][1]), "+v"(b[0][2]), "+v"(b[0][3]), "+v"(b[0][4]),
        "+v"(b[0][5]), "+v"(b[0][6]), "+v"(b[0][7]), "+v"(b[0][8]), "+v"(b[0][9]),
        "+v"(b[1][0]), "+v"(b[1][1]), "+v"(b[1][2]), "+v"(b[1][3]), "+v"(b[1][4]),
        "+v"(b[1][5]), "+v"(b[1][6]), "+v"(b[1][7]), "+v"(b[1][8]), "+v"(b[1][9]));

    if (t > 0) {
      // wait for all 5 slabs' h(t-1): relaxed poll (no per-poll cache inv),
      // then one agent-scope acquire fence (inv L1 + XCD L2).
      if (tid == 0) {
        unsigned tgt = 5u * (unsigned)t;
        while (__hip_atomic_load(cnt + c, __ATOMIC_RELAXED,
                                 __HIP_MEMORY_SCOPE_AGENT) < tgt) {}
        __builtin_amdgcn_fence(__ATOMIC_ACQUIRE, "agent");
      }
      __syncthreads();
    }

    f32x4 acc[2] = {fzero, fzero};
    if (t > 0) {
      short8 af[10];
#pragma unroll
      for (int kk = 0; kk < 10; ++kk)
        af[kk] = *(const short8*)(hhist + (arowb + (t - 1)) * KP + kk * 32 + q * 8);
#pragma unroll
      for (int nt = 0; nt < 2; ++nt) {
        f32x4 a0 = fzero, a1 = fzero;
#pragma unroll
        for (int kk = 0; kk < 5; ++kk) {
          a0 = __builtin_amdgcn_mfma_f32_16x16x32_bf16(af[2 * kk], b[nt][2 * kk], a0, 0, 0, 0);
          a1 = __builtin_amdgcn_mfma_f32_16x16x32_bf16(af[2 * kk + 1], b[nt][2 * kk + 1], a1, 0, 0, 0);
        }
        acc[nt] = a0 + a1;
      }
    }

#pragma unroll
    for (int nt = 0; nt < 2; ++nt) {
      float v0 = acc[nt][0], v1 = acc[nt][1], v2 = acc[nt][2], v3 = acc[nt][3];
      {  // 4x4 quad-lane transpose (lanes within quad swap regs<->cols)
        bool hi = lane & 1;
        float sS = hi ? v0 : v1; float rr = __shfl_xor(sS, 1, 64);
        if (hi) v0 = rr; else v1 = rr;
        sS = hi ? v2 : v3; rr = __shfl_xor(sS, 1, 64);
        if (hi) v2 = rr; else v3 = rr;
      }
      {
        bool hi = lane & 2;
        float sS = hi ? v0 : v2; float rr = __shfl_xor(sS, 2, 64);
        if (hi) v0 = rr; else v2 = rr;
        sS = hi ? v1 : v3; rr = __shfl_xor(sS, 2, 64);
        if (hi) v1 = rr; else v3 = rr;
      }
      float i_ = sigm(v0 + xq[nt].x);
      float f_ = sigm(v1 + xq[nt].y);
      float g_ = tanh_(v2 + xq[nt].z);
      float o_ = sigm(v3 + xq[nt].w);
      float cn = f_ * cst[nt] + i_ * g_;
      cst[nt] = cn;
      float hn = o_ * tanh_(cn);
      hhist[(xrowb + t) * KP + ubase + nt * 4 + aidx] = f2bf(hn);
    }

    if (t < TSTEPS - 1) {
      __syncthreads();  // drain all waves' h stores (vmcnt 0 before barrier)
      if (tid == 0)
        __hip_atomic_fetch_add(cnt + c, 1u, __ATOMIC_RELEASE,
                               __HIP_MEMORY_SCOPE_AGENT);
      // prefetch next step's xq while other slabs finish + poll runs
#pragma unroll
      for (int nt = 0; nt < 2; ++nt)
        xq[nt] = *(const float4*)(xproj + (xrowb + t + 1) * GP + gbase + nt * 16 + 4 * aidx);
    }
  }
}

// ---------------------------------------------------------------------------
// Final correction: out = outb + (1-outb^2) * s2[b]/s1[b]   (DX cancels)
// ---------------------------------------------------------------------------
__global__ __launch_bounds__(256) void k_final(const float* __restrict__ outb,
                                               const float* __restrict__ sums,
                                               float* __restrict__ out) {
  int idx = blockIdx.x * 256 + threadIdx.x;
  if (idx >= BATCH * DIM) return;
  int b = idx / DIM;
  float v = outb[idx];
  out[idx] = v + (1.f - v * v) * (sums[BATCH + b] / sums[b]);
}

// ---------------------------------------------------------------------------
extern "C" void kernel_launch(void* const* d_in, const int* in_sizes, int n_in,
                              void* d_out, int out_size, void* d_ws, size_t ws_size,
                              hipStream_t stream) {
  if (ws_size < WS_NEED) return;

  const float* x    = (const float*)d_in[0];
  const float* Wih1 = (const float*)d_in[1];
  const float* Whh1 = (const float*)d_in[2];
  const float* bih1 = (const float*)d_in[3];
  const float* bhh1 = (const float*)d_in[4];
  const float* Wih2 = (const float*)d_in[5];
  const float* Whh2 = (const float*)d_in[6];
  const float* bih2 = (const float*)d_in[7];
  const float* bhh2 = (const float*)d_in[8];
  const float* Wih3 = (const float*)d_in[9];
  const float* Whh3 = (const float*)d_in[10];
  const float* bih3 = (const float*)d_in[11];
  const float* bhh3 = (const float*)d_in[12];
  const float* Wfc  = (const float*)d_in[13];
  const float* bfc  = (const float*)d_in[14];

  unsigned char* ws = (unsigned char*)d_ws;
  float*          xproj = (float*)(ws + OFF_XPROJ);
  unsigned short* xbf   = (unsigned short*)(ws + OFF_XBF);
  unsigned short* wih1p = (unsigned short*)(ws + OFF_WIH1);
  unsigned short* whh1p = (unsigned short*)(ws + OFF_WHH);
  unsigned short* whh2p = whh1p + (size_t)GP * KP;
  unsigned short* whh3p = whh2p + (size_t)GP * KP;
  unsigned short* wih2p = (unsigned short*)(ws + OFF_WIH23);
  unsigned short* wih3p = wih2p + (size_t)GP * KP;
  unsigned short* wfcp  = (unsigned short*)(ws + OFF_WFC);
  float*          bias1 = (float*)(ws + OFF_BIAS);
  float*          bias2 = bias1 + GP;
  float*          bias3 = bias2 + GP;
  unsigned short* h1    = (unsigned short*)(ws + OFF_H1);
  unsigned short* h2    = (unsigned short*)(ws + OFF_H2);
  unsigned short* h3    = (unsigned short*)(ws + OFF_H3);
  float*          outb  = (float*)(ws + OFF_OUTB);
  float*          sums  = (float*)(ws + OFF_SUMS);
  unsigned int*   cnt   = (unsigned int*)(ws + OFF_CNT);

  k_prep_x<<<(BT * (DP / 8) + 255) / 256, 256, 0, stream>>>(x, xbf);
  k_prep_w<<<(int)((PW_TOTAL + 255) / 256), 256, 0, stream>>>(
      Wih1, Whh1, bih1, bhh1, Wih2, Whh2, bih2, bhh2, Wih3, Whh3, bih3, bhh3, Wfc, ws);

  // layer 1
  k_gemm<0><<<dim3(BT / 128, GP / 128), 256, 0, stream>>>(
      xbf, DP, wih1p, DP, xproj, GP, bias1, nullptr, nullptr);
  k_rec<<<160, 512, 0, stream>>>(xproj, whh1p, h1, cnt + 0 * 32);
  // layer 2
  k_gemm<0><<<dim3(BT / 128, GP / 128), 256, 0, stream>>>(
      h1, KP, wih2p, KP, xproj, GP, bias2, nullptr, nullptr);
  k_rec<<<160, 512, 0, stream>>>(xproj, whh2p, h2, cnt + 1 * 32);
  // layer 3
  k_gemm<0><<<dim3(BT / 128, GP / 128), 256, 0, stream>>>(
      h2, KP, wih3p, KP, xproj, GP, bias3, nullptr, nullptr);
  k_rec<<<160, 512, 0, stream>>>(xproj, whh3p, h3, cnt + 2 * 32);

  // FC + poly_bias + row-sum reduction (A rows = h3 at t=15)
  k_gemm<1><<<dim3(BATCH / 128, DP / 128), 256, 0, stream>>>(
      h3 + (size_t)15 * KP, (long)16 * KP, wfcp, KP, outb, DIM, bfc, x, sums);

  k_final<<<(BATCH * DIM + 255) / 256, 256, 0, stream>>>(outb, sums, (float*)d_out);
}

// Round 5
// 746.467 us; speedup vs baseline: 1.8811x; 1.0658x over previous
//
#include <hip/hip_runtime.h>
#include <hip/hip_bf16.h>
#include <stdint.h>
#include <stddef.h>

// ---------------------------------------------------------------------------
// Problem dims
// ---------------------------------------------------------------------------
constexpr int BATCH = 512, TSTEPS = 16, DIM = 2500, HID = 300;
constexpr int BT = BATCH * TSTEPS;   // 8192
constexpr int GP = 1280;             // padded gate count (4*300 -> 1280)
constexpr int KP = 320;              // padded hidden (300 -> 320)
constexpr int DP = 2560;             // padded DIM (2500 -> 2560)

// ---------------------------------------------------------------------------
// Workspace layout (bytes)
// ---------------------------------------------------------------------------
constexpr size_t OFF_XPROJ = 0;                                  // [8192][1280] f32
constexpr size_t SZ_XPROJ  = (size_t)BT * GP * 4;
constexpr size_t OFF_XBF   = OFF_XPROJ + SZ_XPROJ;               // [8192][2560] bf16
constexpr size_t SZ_XBF    = (size_t)BT * DP * 2;
constexpr size_t OFF_WIH1  = OFF_XBF + SZ_XBF;                   // [1280][2560] bf16 (perm)
constexpr size_t SZ_WIH1   = (size_t)GP * DP * 2;
constexpr size_t OFF_WHH   = OFF_WIH1 + SZ_WIH1;                 // 3x [1280][320] bf16 (perm)
constexpr size_t SZ_WHH1   = (size_t)GP * KP * 2;
constexpr size_t OFF_WIH23 = OFF_WHH + 3 * SZ_WHH1;              // 2x [1280][320] bf16 (perm)
constexpr size_t OFF_WFC   = OFF_WIH23 + 2 * SZ_WHH1;            // [2560][320] bf16
constexpr size_t SZ_WFC    = (size_t)DP * KP * 2;
constexpr size_t OFF_BIAS  = OFF_WFC + SZ_WFC;                   // 3x [1280] f32 (perm bih+bhh)
constexpr size_t OFF_H1    = OFF_BIAS + 3 * GP * 4;              // [8192][320] bf16
constexpr size_t SZ_H      = (size_t)BT * KP * 2;
constexpr size_t OFF_H2    = OFF_H1 + SZ_H;
constexpr size_t OFF_H3    = OFF_H2 + SZ_H;
constexpr size_t OFF_OUTB  = OFF_H3 + SZ_H;                      // [512][2500] f32
constexpr size_t OFF_SUMS  = OFF_OUTB + (size_t)BATCH * DIM * 4; // [2][512] f32
constexpr size_t OFF_CNT   = OFF_SUMS + 2 * BATCH * 4;           // [3][32] u32 sync counters
constexpr size_t WS_NEED   = OFF_CNT + 3 * 32 * 4;

typedef __attribute__((ext_vector_type(8))) short short8;
typedef __attribute__((ext_vector_type(4))) float f32x4;

__device__ __forceinline__ unsigned short f2bf(float f) {
  __hip_bfloat16 h = __float2bfloat16(f);
  return *reinterpret_cast<unsigned short*>(&h);
}

__device__ __forceinline__ void gload_lds16(const void* g, void* l) {
  __builtin_amdgcn_global_load_lds(
      (const __attribute__((address_space(1))) unsigned int*)g,
      (__attribute__((address_space(3))) unsigned int*)l,
      16, 0, 0);
}

__device__ __forceinline__ float sigm(float x) { return 1.f / (1.f + __expf(-x)); }
__device__ __forceinline__ float tanh_(float x) {
  x = fminf(fmaxf(x, -30.f), 30.f);
  float e = __expf(2.f * x);
  return (e - 1.f) / (e + 1.f);
}

// ---------------------------------------------------------------------------
// K0a: x f32 -> bf16 padded [8192][2560]
// ---------------------------------------------------------------------------
__global__ __launch_bounds__(256) void k_prep_x(const float* __restrict__ x,
                                                unsigned short* __restrict__ xbf) {
  int idx = blockIdx.x * 256 + threadIdx.x;       // one thread = 8 outputs
  int row = idx / (DP / 8);
  int k8  = (idx % (DP / 8)) * 8;
  if (row >= BT) return;
  short8 v;
  if (k8 + 8 <= DIM) {
    const float* src = x + (size_t)row * DIM + k8;
    float4 f0 = *(const float4*)(src);
    float4 f1 = *(const float4*)(src + 4);
    v[0] = f2bf(f0.x); v[1] = f2bf(f0.y); v[2] = f2bf(f0.z); v[3] = f2bf(f0.w);
    v[4] = f2bf(f1.x); v[5] = f2bf(f1.y); v[6] = f2bf(f1.z); v[7] = f2bf(f1.w);
  } else {
#pragma unroll
    for (int j = 0; j < 8; ++j) {
      int k = k8 + j;
      float f = (k < DIM) ? x[(size_t)row * DIM + k] : 0.f;
      v[j] = f2bf(f);
    }
  }
  *reinterpret_cast<short8*>(xbf + (size_t)row * DP + k8) = v;
}

// ---------------------------------------------------------------------------
// K0b: all weights -> bf16, gate-permuted (n' = 4*j + g), padded; bias sums;
// zero sums + sync counters
// ---------------------------------------------------------------------------
constexpr long PW_R1 = (long)GP * DP;          // Wih1p
constexpr long PW_R2 = 3L * GP * KP;           // Whh1..3
constexpr long PW_R3 = 2L * GP * KP;           // Wih2,3
constexpr long PW_R4 = (long)DP * KP;          // Wfc
constexpr long PW_R5 = 3L * GP;                // biases
constexpr long PW_R6 = 2L * BATCH + 3 * 32;    // sums + counters zero
constexpr long PW_TOTAL = PW_R1 + PW_R2 + PW_R3 + PW_R4 + PW_R5 + PW_R6;

__global__ __launch_bounds__(256) void k_prep_w(
    const float* __restrict__ Wih1, const float* __restrict__ Whh1,
    const float* __restrict__ bih1, const float* __restrict__ bhh1,
    const float* __restrict__ Wih2, const float* __restrict__ Whh2,
    const float* __restrict__ bih2, const float* __restrict__ bhh2,
    const float* __restrict__ Wih3, const float* __restrict__ Whh3,
    const float* __restrict__ bih3, const float* __restrict__ bhh3,
    const float* __restrict__ Wfc, unsigned char* __restrict__ ws) {
  long i = (long)blockIdx.x * 256 + threadIdx.x;
  if (i < PW_R1) {
    int n = (int)(i / DP), k = (int)(i % DP);
    int j = n >> 2, g = n & 3;
    float f = (j < HID && k < DIM) ? Wih1[(size_t)(g * HID + j) * DIM + k] : 0.f;
    ((unsigned short*)(ws + OFF_WIH1))[i] = f2bf(f);
    return;
  }
  i -= PW_R1;
  if (i < PW_R2) {
    int L = (int)(i / ((long)GP * KP));
    long r = i % ((long)GP * KP);
    int n = (int)(r / KP), k = (int)(r % KP);
    int j = n >> 2, g = n & 3;
    const float* W = (L == 0) ? Whh1 : (L == 1) ? Whh2 : Whh3;
    float f = (j < HID && k < HID) ? W[(size_t)(g * HID + j) * HID + k] : 0.f;
    ((unsigned short*)(ws + OFF_WHH))[i] = f2bf(f);
    return;
  }
  i -= PW_R2;
  if (i < PW_R3) {
    int L = (int)(i / ((long)GP * KP));
    long r = i % ((long)GP * KP);
    int n = (int)(r / KP), k = (int)(r % KP);
    int j = n >> 2, g = n & 3;
    const float* W = (L == 0) ? Wih2 : Wih3;
    float f = (j < HID && k < HID) ? W[(size_t)(g * HID + j) * HID + k] : 0.f;
    ((unsigned short*)(ws + OFF_WIH23))[i] = f2bf(f);
    return;
  }
  i -= PW_R3;
  if (i < PW_R4) {
    int d = (int)(i / KP), k = (int)(i % KP);
    float f = (d < DIM && k < HID) ? Wfc[(size_t)d * HID + k] : 0.f;
    ((unsigned short*)(ws + OFF_WFC))[i] = f2bf(f);
    return;
  }
  i -= PW_R4;
  if (i < PW_R5) {
    int L = (int)(i / GP);
    int n = (int)(i % GP);
    int j = n >> 2, g = n & 3;
    const float* bi = (L == 0) ? bih1 : (L == 1) ? bih2 : bih3;
    const float* bh = (L == 0) ? bhh1 : (L == 1) ? bhh2 : bhh3;
    float f = (j < HID) ? (bi[g * HID + j] + bh[g * HID + j]) : 0.f;
    ((float*)(ws + OFF_BIAS))[i] = f;
    return;
  }
  i -= PW_R5;
  if (i < PW_R6) ((unsigned int*)(ws + OFF_SUMS))[i] = 0u;  // sums + counters
}

// ---------------------------------------------------------------------------
// Generic bf16 NT GEMM (m97 structure): C[M][N] = A[M][K] * B[N][K]^T
// ---------------------------------------------------------------------------
template <int EPI>
__global__ __launch_bounds__(256) void k_gemm(
    const unsigned short* __restrict__ A, long ars,
    const unsigned short* __restrict__ Bm, int K,
    float* __restrict__ C, int ldc,
    const float* __restrict__ bias,
    const float* __restrict__ xsrc, float* __restrict__ sums) {
  __shared__ __align__(16) unsigned char Asm[128 * 64 * 2];
  __shared__ __align__(16) unsigned char Bsm[128 * 64 * 2];
  const int tid = threadIdx.x, lane = tid & 63, w = tid >> 6;
  const int wr = w >> 1, wc = w & 1;
  const int r0 = blockIdx.x * 128;
  const int c0 = blockIdx.y * 128;

  const f32x4 fzero = {0.f, 0.f, 0.f, 0.f};
  f32x4 acc[4][4];
#pragma unroll
  for (int m = 0; m < 4; ++m)
#pragma unroll
    for (int n = 0; n < 4; ++n) acc[m][n] = fzero;

  for (int k0 = 0; k0 < K; k0 += 64) {
#pragma unroll
    for (int i = 0; i < 4; ++i) {
      int base = w * 4096 + i * 1024;
      int beta = base + lane * 16;
      int arow = beta >> 7;
      int acolb = beta & 127;
      const unsigned short* ga = A + (size_t)(r0 + arow) * ars + k0 + (acolb >> 1);
      gload_lds16(ga, (char*)Asm + base);
      const unsigned short* gb = Bm + (size_t)(c0 + arow) * K + k0 + (acolb >> 1);
      gload_lds16(gb, (char*)Bsm + base);
    }
    __syncthreads();
#pragma unroll
    for (int kk = 0; kk < 2; ++kk) {
      short8 af[4], bfg[4];
#pragma unroll
      for (int m = 0; m < 4; ++m)
        af[m] = *(const short8*)(Asm + (wr * 64 + m * 16 + (lane & 15)) * 128 +
                                 kk * 64 + (lane >> 4) * 16);
#pragma unroll
      for (int n = 0; n < 4; ++n)
        bfg[n] = *(const short8*)(Bsm + (wc * 64 + n * 16 + (lane & 15)) * 128 +
                                  kk * 64 + (lane >> 4) * 16);
#pragma unroll
      for (int m = 0; m < 4; ++m)
#pragma unroll
        for (int n = 0; n < 4; ++n)
          acc[m][n] = __builtin_amdgcn_mfma_f32_16x16x32_bf16(af[m], bfg[n], acc[m][n], 0, 0, 0);
    }
    __syncthreads();
  }

  if (EPI == 0) {
#pragma unroll
    for (int m = 0; m < 4; ++m)
#pragma unroll
      for (int n = 0; n < 4; ++n)
#pragma unroll
        for (int r = 0; r < 4; ++r) {
          int row = r0 + wr * 64 + m * 16 + (lane >> 4) * 4 + r;
          int col = c0 + wc * 64 + n * 16 + (lane & 15);
          C[(size_t)row * ldc + col] = acc[m][n][r] + bias[col];
        }
  } else {
    float s1loc[16], s2loc[16];
#pragma unroll
    for (int i = 0; i < 16; ++i) { s1loc[i] = 0.f; s2loc[i] = 0.f; }
#pragma unroll
    for (int m = 0; m < 4; ++m)
#pragma unroll
      for (int n = 0; n < 4; ++n)
#pragma unroll
        for (int r = 0; r < 4; ++r) {
          int row = r0 + wr * 64 + m * 16 + (lane >> 4) * 4 + r;
          int col = c0 + wc * 64 + n * 16 + (lane & 15);
          if (col < DIM) {
            float x13 = xsrc[((size_t)row * 16 + 13) * DIM + col];
            float x14 = xsrc[((size_t)row * 16 + 14) * DIM + col];
            float x15 = xsrc[((size_t)row * 16 + 15) * DIM + col];
            float poly = (x13 + x14 + x15) * (1.f / 3.f) + x15 - x13;
            float v = acc[m][n][r] + bias[col] + poly;
            C[(size_t)row * DIM + col] = v;
            float x0v = xsrc[(size_t)row * 16 * DIM + col];
            s1loc[m * 4 + r] += 1.f - v * v;
            s2loc[m * 4 + r] += x0v - v;
          }
        }
#pragma unroll
    for (int i = 0; i < 16; ++i) {
      float a = s1loc[i], b2 = s2loc[i];
      a += __shfl_xor(a, 1, 64);  b2 += __shfl_xor(b2, 1, 64);
      a += __shfl_xor(a, 2, 64);  b2 += __shfl_xor(b2, 2, 64);
      a += __shfl_xor(a, 4, 64);  b2 += __shfl_xor(b2, 4, 64);
      a += __shfl_xor(a, 8, 64);  b2 += __shfl_xor(b2, 8, 64);
      if ((lane & 15) == 0) {
        int row = r0 + wr * 64 + (i >> 2) * 16 + (lane >> 4) * 4 + (i & 3);
        atomicAdd(&sums[row], a);
        atomicAdd(&sums[BATCH + row], b2);
      }
    }
  }
}

// ---------------------------------------------------------------------------
// LSTM recurrence v4: gate-split across 5 blocks per batch-chunk.
// Whh slab loaded ONCE via opaque inline-asm global_load_dwordx4 (cannot be
// rematerialized/sunk -> register-resident). Producer: syncthreads + agent-
// RELEASE fetch_add (L2 wb to L3). Consumer: RELAXED poll + workgroup-acquire
// only -- NO cache invalidation. Correct because every hhist line (one 128B
// line per row x slab) is written by exactly one producer before its release
// and first touched by consumers only after the poll succeeds.
// ---------------------------------------------------------------------------
__global__ __launch_bounds__(512, 2) void k_rec(
    const float* __restrict__ xproj,        // [8192][1280] f32, bias folded
    const unsigned short* __restrict__ Whh, // [1280][320] bf16 permuted
    unsigned short* __restrict__ hhist,     // [8192][320] bf16
    unsigned int* __restrict__ cnt) {       // [32] zeroed
  const int tid = threadIdx.x, lane = tid & 63, w = tid >> 6;  // 8 waves
  const int c = blockIdx.x & 31;        // batch chunk (16 rows)
  const int s = blockIdx.x >> 5;        // gate slab 0..4
  const int gbase = s * 256 + w * 32;   // first gate owned by this wave
  const int l15 = lane & 15, q = lane >> 4;

  // --- persistent B fragments: 32 gates x 320 K in VGPRs (80 regs) ---
  // Opaque asm loads: compiler cannot re-materialize these in the loop.
  short8 b[2][10];
  {
    const unsigned short* p0 = Whh + (size_t)(gbase + l15) * KP + q * 8;
    const unsigned short* p1 = Whh + (size_t)(gbase + 16 + l15) * KP + q * 8;
#pragma unroll
    for (int kk = 0; kk < 10; ++kk) {
      asm volatile("global_load_dwordx4 %0, %1, off offset:%2"
                   : "=v"(b[0][kk]) : "v"(p0), "i"(kk * 64));
      asm volatile("global_load_dwordx4 %0, %1, off offset:%2"
                   : "=v"(b[1][kk]) : "v"(p1), "i"(kk * 64));
    }
    asm volatile("s_waitcnt vmcnt(0)" ::: "memory");
    __builtin_amdgcn_sched_barrier(0);
  }

  const int m2 = q * 4 + (lane & 3);     // post-transpose batch row
  const int aidx = (lane >> 2) & 3;      // unit within 16-gate tile
  const int ubase = s * 64 + w * 8;      // first h-unit owned by this wave
  const f32x4 fzero = {0.f, 0.f, 0.f, 0.f};

  float cst[2] = {0.f, 0.f};
  const size_t xrowb = (size_t)(c * 16 + m2) * 16;          // xproj/hhist row (m2)
  const size_t arowb = (size_t)(c * 16 + l15) * 16;         // hhist row (A-frag)

  float4 xq[2];
#pragma unroll
  for (int nt = 0; nt < 2; ++nt)
    xq[nt] = *(const float4*)(xproj + xrowb * GP + gbase + nt * 16 + 4 * aidx);

  for (int t = 0; t < TSTEPS; ++t) {
    if (t > 0) {
      // Wait for all 5 slabs' h(t-1). Relaxed poll (no cache ops), then a
      // workgroup-scope acquire (waitcnt only; ordering for the IR). The
      // data lines are fresh (first touch) so no L1/L2 invalidate needed.
      if (tid == 0) {
        unsigned tgt = 5u * (unsigned)t;
        while (__hip_atomic_load(cnt + c, __ATOMIC_RELAXED,
                                 __HIP_MEMORY_SCOPE_AGENT) < tgt) {}
        __builtin_amdgcn_fence(__ATOMIC_ACQUIRE, "workgroup");
      }
      __syncthreads();
    }

    f32x4 acc[2] = {fzero, fzero};
    if (t > 0) {
      short8 af[10];
#pragma unroll
      for (int kk = 0; kk < 10; ++kk)
        af[kk] = *(const short8*)(hhist + (arowb + (t - 1)) * KP + kk * 32 + q * 8);
#pragma unroll
      for (int nt = 0; nt < 2; ++nt) {
        f32x4 a0 = fzero, a1 = fzero;
#pragma unroll
        for (int kk = 0; kk < 5; ++kk) {
          a0 = __builtin_amdgcn_mfma_f32_16x16x32_bf16(af[2 * kk], b[nt][2 * kk], a0, 0, 0, 0);
          a1 = __builtin_amdgcn_mfma_f32_16x16x32_bf16(af[2 * kk + 1], b[nt][2 * kk + 1], a1, 0, 0, 0);
        }
        acc[nt] = a0 + a1;
      }
    }

#pragma unroll
    for (int nt = 0; nt < 2; ++nt) {
      float v0 = acc[nt][0], v1 = acc[nt][1], v2 = acc[nt][2], v3 = acc[nt][3];
      {  // 4x4 quad-lane transpose (lanes within quad swap regs<->cols)
        bool hi = lane & 1;
        float sS = hi ? v0 : v1; float rr = __shfl_xor(sS, 1, 64);
        if (hi) v0 = rr; else v1 = rr;
        sS = hi ? v2 : v3; rr = __shfl_xor(sS, 1, 64);
        if (hi) v2 = rr; else v3 = rr;
      }
      {
        bool hi = lane & 2;
        float sS = hi ? v0 : v2; float rr = __shfl_xor(sS, 2, 64);
        if (hi) v0 = rr; else v2 = rr;
        sS = hi ? v1 : v3; rr = __shfl_xor(sS, 2, 64);
        if (hi) v1 = rr; else v3 = rr;
      }
      float i_ = sigm(v0 + xq[nt].x);
      float f_ = sigm(v1 + xq[nt].y);
      float g_ = tanh_(v2 + xq[nt].z);
      float o_ = sigm(v3 + xq[nt].w);
      float cn = f_ * cst[nt] + i_ * g_;
      cst[nt] = cn;
      float hn = o_ * tanh_(cn);
      hhist[(xrowb + t) * KP + ubase + nt * 4 + aidx] = f2bf(hn);
    }

    if (t < TSTEPS - 1) {
      __syncthreads();  // drain all waves' h stores (vmcnt 0 before barrier)
      if (tid == 0)
        __hip_atomic_fetch_add(cnt + c, 1u, __ATOMIC_RELEASE,
                               __HIP_MEMORY_SCOPE_AGENT);
      // prefetch next step's xq while other slabs finish + poll runs
#pragma unroll
      for (int nt = 0; nt < 2; ++nt)
        xq[nt] = *(const float4*)(xproj + (xrowb + t + 1) * GP + gbase + nt * 16 + 4 * aidx);
    }
  }
}

// ---------------------------------------------------------------------------
// Final correction: out = outb + (1-outb^2) * s2[b]/s1[b]   (DX cancels)
// ---------------------------------------------------------------------------
__global__ __launch_bounds__(256) void k_final(const float* __restrict__ outb,
                                               const float* __restrict__ sums,
                                               float* __restrict__ out) {
  int idx = blockIdx.x * 256 + threadIdx.x;
  if (idx >= BATCH * DIM) return;
  int b = idx / DIM;
  float v = outb[idx];
  out[idx] = v + (1.f - v * v) * (sums[BATCH + b] / sums[b]);
}

// ---------------------------------------------------------------------------
extern "C" void kernel_launch(void* const* d_in, const int* in_sizes, int n_in,
                              void* d_out, int out_size, void* d_ws, size_t ws_size,
                              hipStream_t stream) {
  if (ws_size < WS_NEED) return;

  const float* x    = (const float*)d_in[0];
  const float* Wih1 = (const float*)d_in[1];
  const float* Whh1 = (const float*)d_in[2];
  const float* bih1 = (const float*)d_in[3];
  const float* bhh1 = (const float*)d_in[4];
  const float* Wih2 = (const float*)d_in[5];
  const float* Whh2 = (const float*)d_in[6];
  const float* bih2 = (const float*)d_in[7];
  const float* bhh2 = (const float*)d_in[8];
  const float* Wih3 = (const float*)d_in[9];
  const float* Whh3 = (const float*)d_in[10];
  const float* bih3 = (const float*)d_in[11];
  const float* bhh3 = (const float*)d_in[12];
  const float* Wfc  = (const float*)d_in[13];
  const float* bfc  = (const float*)d_in[14];

  unsigned char* ws = (unsigned char*)d_ws;
  float*          xproj = (float*)(ws + OFF_XPROJ);
  unsigned short* xbf   = (unsigned short*)(ws + OFF_XBF);
  unsigned short* wih1p = (unsigned short*)(ws + OFF_WIH1);
  unsigned short* whh1p = (unsigned short*)(ws + OFF_WHH);
  unsigned short* whh2p = whh1p + (size_t)GP * KP;
  unsigned short* whh3p = whh2p + (size_t)GP * KP;
  unsigned short* wih2p = (unsigned short*)(ws + OFF_WIH23);
  unsigned short* wih3p = wih2p + (size_t)GP * KP;
  unsigned short* wfcp  = (unsigned short*)(ws + OFF_WFC);
  float*          bias1 = (float*)(ws + OFF_BIAS);
  float*          bias2 = bias1 + GP;
  float*          bias3 = bias2 + GP;
  unsigned short* h1    = (unsigned short*)(ws + OFF_H1);
  unsigned short* h2    = (unsigned short*)(ws + OFF_H2);
  unsigned short* h3    = (unsigned short*)(ws + OFF_H3);
  float*          outb  = (float*)(ws + OFF_OUTB);
  float*          sums  = (float*)(ws + OFF_SUMS);
  unsigned int*   cnt   = (unsigned int*)(ws + OFF_CNT);

  k_prep_x<<<(BT * (DP / 8) + 255) / 256, 256, 0, stream>>>(x, xbf);
  k_prep_w<<<(int)((PW_TOTAL + 255) / 256), 256, 0, stream>>>(
      Wih1, Whh1, bih1, bhh1, Wih2, Whh2, bih2, bhh2, Wih3, Whh3, bih3, bhh3, Wfc, ws);

  // layer 1
  k_gemm<0><<<dim3(BT / 128, GP / 128), 256, 0, stream>>>(
      xbf, DP, wih1p, DP, xproj, GP, bias1, nullptr, nullptr);
  k_rec<<<160, 512, 0, stream>>>(xproj, whh1p, h1, cnt + 0 * 32);
  // layer 2
  k_gemm<0><<<dim3(BT / 128, GP / 128), 256, 0, stream>>>(
      h1, KP, wih2p, KP, xproj, GP, bias2, nullptr, nullptr);
  k_rec<<<160, 512, 0, stream>>>(xproj, whh2p, h2, cnt + 1 * 32);
  // layer 3
  k_gemm<0><<<dim3(BT / 128, GP / 128), 256, 0, stream>>>(
      h2, KP, wih3p, KP, xproj, GP, bias3, nullptr, nullptr);
  k_rec<<<160, 512, 0, stream>>>(xproj, whh3p, h3, cnt + 2 * 32);

  // FC + poly_bias + row-sum reduction (A rows = h3 at t=15)
  k_gemm<1><<<dim3(BATCH / 128, DP / 128), 256, 0, stream>>>(
      h3 + (size_t)15 * KP, (long)16 * KP, wfcp, KP, outb, DIM, bfc, x, sums);

  k_final<<<(BATCH * DIM + 255) / 256, 256, 0, stream>>>(outb, sums, (float*)d_out);
}

// Round 6
// 730.158 us; speedup vs baseline: 1.9231x; 1.0223x over previous
//
#include <hip/hip_runtime.h>
#include <hip/hip_bf16.h>
#include <stdint.h>
#include <stddef.h>

// ---------------------------------------------------------------------------
// Problem dims
// ---------------------------------------------------------------------------
constexpr int BATCH = 512, TSTEPS = 16, DIM = 2500, HID = 300;
constexpr int BT = BATCH * TSTEPS;   // 8192
constexpr int GP = 1280;             // padded gate count (4*300 -> 1280)
constexpr int KP = 320;              // padded hidden (300 -> 320)
constexpr int DP = 2560;             // padded DIM (2500 -> 2560)

// ---------------------------------------------------------------------------
// Workspace layout (bytes)
// ---------------------------------------------------------------------------
constexpr size_t OFF_XPROJ = 0;                                  // [8192][1280] f32
constexpr size_t SZ_XPROJ  = (size_t)BT * GP * 4;
constexpr size_t OFF_XBF   = OFF_XPROJ + SZ_XPROJ;               // [8192][2560] bf16
constexpr size_t SZ_XBF    = (size_t)BT * DP * 2;
constexpr size_t OFF_WIH1  = OFF_XBF + SZ_XBF;                   // [1280][2560] bf16 (perm)
constexpr size_t SZ_WIH1   = (size_t)GP * DP * 2;
constexpr size_t OFF_WHH   = OFF_WIH1 + SZ_WIH1;                 // 3x [1280][320] bf16 (perm)
constexpr size_t SZ_WHH1   = (size_t)GP * KP * 2;
constexpr size_t OFF_WIH23 = OFF_WHH + 3 * SZ_WHH1;              // 2x [1280][320] bf16 (perm)
constexpr size_t OFF_WFC   = OFF_WIH23 + 2 * SZ_WHH1;            // [2560][320] bf16
constexpr size_t SZ_WFC    = (size_t)DP * KP * 2;
constexpr size_t OFF_BIAS  = OFF_WFC + SZ_WFC;                   // 3x [1280] f32 (perm bih+bhh)
constexpr size_t OFF_H1    = OFF_BIAS + 3 * GP * 4;              // [8192][320] bf16
constexpr size_t SZ_H      = (size_t)BT * KP * 2;
constexpr size_t OFF_H2    = OFF_H1 + SZ_H;
constexpr size_t OFF_H3    = OFF_H2 + SZ_H;
constexpr size_t OFF_OUTB  = OFF_H3 + SZ_H;                      // [512][2500] f32
constexpr size_t OFF_SUMS  = OFF_OUTB + (size_t)BATCH * DIM * 4; // [2][512] f32
constexpr size_t OFF_CNT   = OFF_SUMS + 2 * BATCH * 4;           // [3][32] u32 sync counters
constexpr size_t WS_NEED   = OFF_CNT + 3 * 32 * 4;

typedef __attribute__((ext_vector_type(8))) short short8;
typedef __attribute__((ext_vector_type(4))) float f32x4;

__device__ __forceinline__ unsigned short f2bf(float f) {
  __hip_bfloat16 h = __float2bfloat16(f);
  return *reinterpret_cast<unsigned short*>(&h);
}

__device__ __forceinline__ void gload_lds16(const void* g, void* l) {
  __builtin_amdgcn_global_load_lds(
      (const __attribute__((address_space(1))) unsigned int*)g,
      (__attribute__((address_space(3))) unsigned int*)l,
      16, 0, 0);
}

__device__ __forceinline__ float sigm(float x) { return 1.f / (1.f + __expf(-x)); }
__device__ __forceinline__ float tanh_(float x) {
  x = fminf(fmaxf(x, -30.f), 30.f);
  float e = __expf(2.f * x);
  return (e - 1.f) / (e + 1.f);
}

// ---------------------------------------------------------------------------
// K0a: x f32 -> bf16 padded [8192][2560]
// ---------------------------------------------------------------------------
__global__ __launch_bounds__(256) void k_prep_x(const float* __restrict__ x,
                                                unsigned short* __restrict__ xbf) {
  int idx = blockIdx.x * 256 + threadIdx.x;       // one thread = 8 outputs
  int row = idx / (DP / 8);
  int k8  = (idx % (DP / 8)) * 8;
  if (row >= BT) return;
  short8 v;
  if (k8 + 8 <= DIM) {
    const float* src = x + (size_t)row * DIM + k8;
    float4 f0 = *(const float4*)(src);
    float4 f1 = *(const float4*)(src + 4);
    v[0] = f2bf(f0.x); v[1] = f2bf(f0.y); v[2] = f2bf(f0.z); v[3] = f2bf(f0.w);
    v[4] = f2bf(f1.x); v[5] = f2bf(f1.y); v[6] = f2bf(f1.z); v[7] = f2bf(f1.w);
  } else {
#pragma unroll
    for (int j = 0; j < 8; ++j) {
      int k = k8 + j;
      float f = (k < DIM) ? x[(size_t)row * DIM + k] : 0.f;
      v[j] = f2bf(f);
    }
  }
  *reinterpret_cast<short8*>(xbf + (size_t)row * DP + k8) = v;
}

// ---------------------------------------------------------------------------
// K0b: all weights -> bf16, gate-permuted (n' = 4*j + g), padded; bias sums;
// zero sums + sync counters
// ---------------------------------------------------------------------------
constexpr long PW_R1 = (long)GP * DP;          // Wih1p
constexpr long PW_R2 = 3L * GP * KP;           // Whh1..3
constexpr long PW_R3 = 2L * GP * KP;           // Wih2,3
constexpr long PW_R4 = (long)DP * KP;          // Wfc
constexpr long PW_R5 = 3L * GP;                // biases
constexpr long PW_R6 = 2L * BATCH + 3 * 32;    // sums + counters zero
constexpr long PW_TOTAL = PW_R1 + PW_R2 + PW_R3 + PW_R4 + PW_R5 + PW_R6;

__global__ __launch_bounds__(256) void k_prep_w(
    const float* __restrict__ Wih1, const float* __restrict__ Whh1,
    const float* __restrict__ bih1, const float* __restrict__ bhh1,
    const float* __restrict__ Wih2, const float* __restrict__ Whh2,
    const float* __restrict__ bih2, const float* __restrict__ bhh2,
    const float* __restrict__ Wih3, const float* __restrict__ Whh3,
    const float* __restrict__ bih3, const float* __restrict__ bhh3,
    const float* __restrict__ Wfc, unsigned char* __restrict__ ws) {
  long i = (long)blockIdx.x * 256 + threadIdx.x;
  if (i < PW_R1) {
    int n = (int)(i / DP), k = (int)(i % DP);
    int j = n >> 2, g = n & 3;
    float f = (j < HID && k < DIM) ? Wih1[(size_t)(g * HID + j) * DIM + k] : 0.f;
    ((unsigned short*)(ws + OFF_WIH1))[i] = f2bf(f);
    return;
  }
  i -= PW_R1;
  if (i < PW_R2) {
    int L = (int)(i / ((long)GP * KP));
    long r = i % ((long)GP * KP);
    int n = (int)(r / KP), k = (int)(r % KP);
    int j = n >> 2, g = n & 3;
    const float* W = (L == 0) ? Whh1 : (L == 1) ? Whh2 : Whh3;
    float f = (j < HID && k < HID) ? W[(size_t)(g * HID + j) * HID + k] : 0.f;
    ((unsigned short*)(ws + OFF_WHH))[i] = f2bf(f);
    return;
  }
  i -= PW_R2;
  if (i < PW_R3) {
    int L = (int)(i / ((long)GP * KP));
    long r = i % ((long)GP * KP);
    int n = (int)(r / KP), k = (int)(r % KP);
    int j = n >> 2, g = n & 3;
    const float* W = (L == 0) ? Wih2 : Wih3;
    float f = (j < HID && k < HID) ? W[(size_t)(g * HID + j) * HID + k] : 0.f;
    ((unsigned short*)(ws + OFF_WIH23))[i] = f2bf(f);
    return;
  }
  i -= PW_R3;
  if (i < PW_R4) {
    int d = (int)(i / KP), k = (int)(i % KP);
    float f = (d < DIM && k < HID) ? Wfc[(size_t)d * HID + k] : 0.f;
    ((unsigned short*)(ws + OFF_WFC))[i] = f2bf(f);
    return;
  }
  i -= PW_R4;
  if (i < PW_R5) {
    int L = (int)(i / GP);
    int n = (int)(i % GP);
    int j = n >> 2, g = n & 3;
    const float* bi = (L == 0) ? bih1 : (L == 1) ? bih2 : bih3;
    const float* bh = (L == 0) ? bhh1 : (L == 1) ? bhh2 : bhh3;
    float f = (j < HID) ? (bi[g * HID + j] + bh[g * HID + j]) : 0.f;
    ((float*)(ws + OFF_BIAS))[i] = f;
    return;
  }
  i -= PW_R5;
  if (i < PW_R6) ((unsigned int*)(ws + OFF_SUMS))[i] = 0u;  // sums + counters
}

// ---------------------------------------------------------------------------
// Generic bf16 NT GEMM (m97 structure): C[M][N] = A[M][K] * B[N][K]^T
// ---------------------------------------------------------------------------
template <int EPI>
__global__ __launch_bounds__(256) void k_gemm(
    const unsigned short* __restrict__ A, long ars,
    const unsigned short* __restrict__ Bm, int K,
    float* __restrict__ C, int ldc,
    const float* __restrict__ bias,
    const float* __restrict__ xsrc, float* __restrict__ sums) {
  __shared__ __align__(16) unsigned char Asm[128 * 64 * 2];
  __shared__ __align__(16) unsigned char Bsm[128 * 64 * 2];
  const int tid = threadIdx.x, lane = tid & 63, w = tid >> 6;
  const int wr = w >> 1, wc = w & 1;
  const int r0 = blockIdx.x * 128;
  const int c0 = blockIdx.y * 128;

  const f32x4 fzero = {0.f, 0.f, 0.f, 0.f};
  f32x4 acc[4][4];
#pragma unroll
  for (int m = 0; m < 4; ++m)
#pragma unroll
    for (int n = 0; n < 4; ++n) acc[m][n] = fzero;

  for (int k0 = 0; k0 < K; k0 += 64) {
#pragma unroll
    for (int i = 0; i < 4; ++i) {
      int base = w * 4096 + i * 1024;
      int beta = base + lane * 16;
      int arow = beta >> 7;
      int acolb = beta & 127;
      const unsigned short* ga = A + (size_t)(r0 + arow) * ars + k0 + (acolb >> 1);
      gload_lds16(ga, (char*)Asm + base);
      const unsigned short* gb = Bm + (size_t)(c0 + arow) * K + k0 + (acolb >> 1);
      gload_lds16(gb, (char*)Bsm + base);
    }
    __syncthreads();
#pragma unroll
    for (int kk = 0; kk < 2; ++kk) {
      short8 af[4], bfg[4];
#pragma unroll
      for (int m = 0; m < 4; ++m)
        af[m] = *(const short8*)(Asm + (wr * 64 + m * 16 + (lane & 15)) * 128 +
                                 kk * 64 + (lane >> 4) * 16);
#pragma unroll
      for (int n = 0; n < 4; ++n)
        bfg[n] = *(const short8*)(Bsm + (wc * 64 + n * 16 + (lane & 15)) * 128 +
                                  kk * 64 + (lane >> 4) * 16);
#pragma unroll
      for (int m = 0; m < 4; ++m)
#pragma unroll
        for (int n = 0; n < 4; ++n)
          acc[m][n] = __builtin_amdgcn_mfma_f32_16x16x32_bf16(af[m], bfg[n], acc[m][n], 0, 0, 0);
    }
    __syncthreads();
  }

  if (EPI == 0) {
#pragma unroll
    for (int m = 0; m < 4; ++m)
#pragma unroll
      for (int n = 0; n < 4; ++n)
#pragma unroll
        for (int r = 0; r < 4; ++r) {
          int row = r0 + wr * 64 + m * 16 + (lane >> 4) * 4 + r;
          int col = c0 + wc * 64 + n * 16 + (lane & 15);
          C[(size_t)row * ldc + col] = acc[m][n][r] + bias[col];
        }
  } else {
    float s1loc[16], s2loc[16];
#pragma unroll
    for (int i = 0; i < 16; ++i) { s1loc[i] = 0.f; s2loc[i] = 0.f; }
#pragma unroll
    for (int m = 0; m < 4; ++m)
#pragma unroll
      for (int n = 0; n < 4; ++n)
#pragma unroll
        for (int r = 0; r < 4; ++r) {
          int row = r0 + wr * 64 + m * 16 + (lane >> 4) * 4 + r;
          int col = c0 + wc * 64 + n * 16 + (lane & 15);
          if (col < DIM) {
            float x13 = xsrc[((size_t)row * 16 + 13) * DIM + col];
            float x14 = xsrc[((size_t)row * 16 + 14) * DIM + col];
            float x15 = xsrc[((size_t)row * 16 + 15) * DIM + col];
            float poly = (x13 + x14 + x15) * (1.f / 3.f) + x15 - x13;
            float v = acc[m][n][r] + bias[col] + poly;
            C[(size_t)row * DIM + col] = v;
            float x0v = xsrc[(size_t)row * 16 * DIM + col];
            s1loc[m * 4 + r] += 1.f - v * v;
            s2loc[m * 4 + r] += x0v - v;
          }
        }
#pragma unroll
    for (int i = 0; i < 16; ++i) {
      float a = s1loc[i], b2 = s2loc[i];
      a += __shfl_xor(a, 1, 64);  b2 += __shfl_xor(b2, 1, 64);
      a += __shfl_xor(a, 2, 64);  b2 += __shfl_xor(b2, 2, 64);
      a += __shfl_xor(a, 4, 64);  b2 += __shfl_xor(b2, 4, 64);
      a += __shfl_xor(a, 8, 64);  b2 += __shfl_xor(b2, 8, 64);
      if ((lane & 15) == 0) {
        int row = r0 + wr * 64 + (i >> 2) * 16 + (lane >> 4) * 4 + (i & 3);
        atomicAdd(&sums[row], a);
        atomicAdd(&sums[BATCH + row], b2);
      }
    }
  }
}

// ---------------------------------------------------------------------------
// LSTM recurrence v5: gate-split across 5 blocks per batch-chunk.
// ZERO cache-maintenance sync protocol:
//   producer: h stores write-through to LLC (global_store_short sc0 sc1),
//             s_waitcnt vmcnt(0), __syncthreads, RELAXED agent fetch_add
//             (atomic RMW is device-coherent by itself; no buffer_wbl2).
//   consumer: RELAXED agent poll + workgroup-acquire (waitcnt only; no inv).
// Correct cross-XCD: every hhist line is in LLC before the counter bump and
// is first-touch for every consumer cache level.
// ---------------------------------------------------------------------------
__global__ __launch_bounds__(512, 2) void k_rec(
    const float* __restrict__ xproj,        // [8192][1280] f32, bias folded
    const unsigned short* __restrict__ Whh, // [1280][320] bf16 permuted
    unsigned short* __restrict__ hhist,     // [8192][320] bf16
    unsigned int* __restrict__ cnt) {       // [32] zeroed
  const int tid = threadIdx.x, lane = tid & 63, w = tid >> 6;  // 8 waves
  const int c = blockIdx.x & 31;        // batch chunk (16 rows)
  const int s = blockIdx.x >> 5;        // gate slab 0..4
  const int gbase = s * 256 + w * 32;   // first gate owned by this wave
  const int l15 = lane & 15, q = lane >> 4;

  // --- persistent B fragments: 32 gates x 320 K in VGPRs (80 regs) ---
  // Opaque asm loads: compiler cannot re-materialize these in the loop.
  short8 b[2][10];
  {
    const unsigned short* p0 = Whh + (size_t)(gbase + l15) * KP + q * 8;
    const unsigned short* p1 = Whh + (size_t)(gbase + 16 + l15) * KP + q * 8;
#pragma unroll
    for (int kk = 0; kk < 10; ++kk) {
      asm volatile("global_load_dwordx4 %0, %1, off offset:%2"
                   : "=v"(b[0][kk]) : "v"(p0), "i"(kk * 64));
      asm volatile("global_load_dwordx4 %0, %1, off offset:%2"
                   : "=v"(b[1][kk]) : "v"(p1), "i"(kk * 64));
    }
    asm volatile("s_waitcnt vmcnt(0)" ::: "memory");
    __builtin_amdgcn_sched_barrier(0);
  }

  const int m2 = q * 4 + (lane & 3);     // post-transpose batch row
  const int aidx = (lane >> 2) & 3;      // unit within 16-gate tile
  const int ubase = s * 64 + w * 8;      // first h-unit owned by this wave
  const f32x4 fzero = {0.f, 0.f, 0.f, 0.f};

  float cst[2] = {0.f, 0.f};
  const size_t xrowb = (size_t)(c * 16 + m2) * 16;          // xproj/hhist row (m2)
  const size_t arowb = (size_t)(c * 16 + l15) * 16;         // hhist row (A-frag)

  float4 xq[2];
#pragma unroll
  for (int nt = 0; nt < 2; ++nt)
    xq[nt] = *(const float4*)(xproj + xrowb * GP + gbase + nt * 16 + 4 * aidx);

  for (int t = 0; t < TSTEPS; ++t) {
    if (t > 0) {
      // Wait for all 5 slabs' h(t-1). Relaxed poll (no cache ops), then a
      // workgroup-scope acquire (waitcnt only). Data lines are first-touch
      // and already at LLC (sc0/sc1 write-through) -> no invalidate needed.
      if (tid == 0) {
        unsigned tgt = 5u * (unsigned)t;
        while (__hip_atomic_load(cnt + c, __ATOMIC_RELAXED,
                                 __HIP_MEMORY_SCOPE_AGENT) < tgt) {}
        __builtin_amdgcn_fence(__ATOMIC_ACQUIRE, "workgroup");
      }
      __syncthreads();
    }

    f32x4 acc[2] = {fzero, fzero};
    if (t > 0) {
      short8 af[10];
#pragma unroll
      for (int kk = 0; kk < 10; ++kk)
        af[kk] = *(const short8*)(hhist + (arowb + (t - 1)) * KP + kk * 32 + q * 8);
#pragma unroll
      for (int nt = 0; nt < 2; ++nt) {
        f32x4 a0 = fzero, a1 = fzero;
#pragma unroll
        for (int kk = 0; kk < 5; ++kk) {
          a0 = __builtin_amdgcn_mfma_f32_16x16x32_bf16(af[2 * kk], b[nt][2 * kk], a0, 0, 0, 0);
          a1 = __builtin_amdgcn_mfma_f32_16x16x32_bf16(af[2 * kk + 1], b[nt][2 * kk + 1], a1, 0, 0, 0);
        }
        acc[nt] = a0 + a1;
      }
    }

#pragma unroll
    for (int nt = 0; nt < 2; ++nt) {
      float v0 = acc[nt][0], v1 = acc[nt][1], v2 = acc[nt][2], v3 = acc[nt][3];
      {  // 4x4 quad-lane transpose (lanes within quad swap regs<->cols)
        bool hi = lane & 1;
        float sS = hi ? v0 : v1; float rr = __shfl_xor(sS, 1, 64);
        if (hi) v0 = rr; else v1 = rr;
        sS = hi ? v2 : v3; rr = __shfl_xor(sS, 1, 64);
        if (hi) v2 = rr; else v3 = rr;
      }
      {
        bool hi = lane & 2;
        float sS = hi ? v0 : v2; float rr = __shfl_xor(sS, 2, 64);
        if (hi) v0 = rr; else v2 = rr;
        sS = hi ? v1 : v3; rr = __shfl_xor(sS, 2, 64);
        if (hi) v1 = rr; else v3 = rr;
      }
      float i_ = sigm(v0 + xq[nt].x);
      float f_ = sigm(v1 + xq[nt].y);
      float g_ = tanh_(v2 + xq[nt].z);
      float o_ = sigm(v3 + xq[nt].w);
      float cn = f_ * cst[nt] + i_ * g_;
      cst[nt] = cn;
      float hn = o_ * tanh_(cn);
      // write-through store: visible at LLC once vmcnt drains
      unsigned short* hp = hhist + (xrowb + t) * KP + ubase + nt * 4 + aidx;
      unsigned hv = (unsigned)f2bf(hn);
      asm volatile("global_store_short %0, %1, off sc0 sc1"
                   :: "v"(hp), "v"(hv) : "memory");
    }

    if (t < TSTEPS - 1) {
      asm volatile("s_waitcnt vmcnt(0)" ::: "memory");  // h at LLC
      __syncthreads();
      if (tid == 0)
        __hip_atomic_fetch_add(cnt + c, 1u, __ATOMIC_RELAXED,
                               __HIP_MEMORY_SCOPE_AGENT);
      // prefetch next step's xq while other slabs finish + poll runs
#pragma unroll
      for (int nt = 0; nt < 2; ++nt)
        xq[nt] = *(const float4*)(xproj + (xrowb + t + 1) * GP + gbase + nt * 16 + 4 * aidx);
    }
  }
}

// ---------------------------------------------------------------------------
// Final correction: out = outb + (1-outb^2) * s2[b]/s1[b]   (DX cancels)
// ---------------------------------------------------------------------------
__global__ __launch_bounds__(256) void k_final(const float* __restrict__ outb,
                                               const float* __restrict__ sums,
                                               float* __restrict__ out) {
  int idx = blockIdx.x * 256 + threadIdx.x;
  if (idx >= BATCH * DIM) return;
  int b = idx / DIM;
  float v = outb[idx];
  out[idx] = v + (1.f - v * v) * (sums[BATCH + b] / sums[b]);
}

// ---------------------------------------------------------------------------
extern "C" void kernel_launch(void* const* d_in, const int* in_sizes, int n_in,
                              void* d_out, int out_size, void* d_ws, size_t ws_size,
                              hipStream_t stream) {
  if (ws_size < WS_NEED) return;

  const float* x    = (const float*)d_in[0];
  const float* Wih1 = (const float*)d_in[1];
  const float* Whh1 = (const float*)d_in[2];
  const float* bih1 = (const float*)d_in[3];
  const float* bhh1 = (const float*)d_in[4];
  const float* Wih2 = (const float*)d_in[5];
  const float* Whh2 = (const float*)d_in[6];
  const float* bih2 = (const float*)d_in[7];
  const float* bhh2 = (const float*)d_in[8];
  const float* Wih3 = (const float*)d_in[9];
  const float* Whh3 = (const float*)d_in[10];
  const float* bih3 = (const float*)d_in[11];
  const float* bhh3 = (const float*)d_in[12];
  const float* Wfc  = (const float*)d_in[13];
  const float* bfc  = (const float*)d_in[14];

  unsigned char* ws = (unsigned char*)d_ws;
  float*          xproj = (float*)(ws + OFF_XPROJ);
  unsigned short* xbf   = (unsigned short*)(ws + OFF_XBF);
  unsigned short* wih1p = (unsigned short*)(ws + OFF_WIH1);
  unsigned short* whh1p = (unsigned short*)(ws + OFF_WHH);
  unsigned short* whh2p = whh1p + (size_t)GP * KP;
  unsigned short* whh3p = whh2p + (size_t)GP * KP;
  unsigned short* wih2p = (unsigned short*)(ws + OFF_WIH23);
  unsigned short* wih3p = wih2p + (size_t)GP * KP;
  unsigned short* wfcp  = (unsigned short*)(ws + OFF_WFC);
  float*          bias1 = (float*)(ws + OFF_BIAS);
  float*          bias2 = bias1 + GP;
  float*          bias3 = bias2 + GP;
  unsigned short* h1    = (unsigned short*)(ws + OFF_H1);
  unsigned short* h2    = (unsigned short*)(ws + OFF_H2);
  unsigned short* h3    = (unsigned short*)(ws + OFF_H3);
  float*          outb  = (float*)(ws + OFF_OUTB);
  float*          sums  = (float*)(ws + OFF_SUMS);
  unsigned int*   cnt   = (unsigned int*)(ws + OFF_CNT);

  k_prep_x<<<(BT * (DP / 8) + 255) / 256, 256, 0, stream>>>(x, xbf);
  k_prep_w<<<(int)((PW_TOTAL + 255) / 256), 256, 0, stream>>>(
      Wih1, Whh1, bih1, bhh1, Wih2, Whh2, bih2, bhh2, Wih3, Whh3, bih3, bhh3, Wfc, ws);

  // layer 1
  k_gemm<0><<<dim3(BT / 128, GP / 128), 256, 0, stream>>>(
      xbf, DP, wih1p, DP, xproj, GP, bias1, nullptr, nullptr);
  k_rec<<<160, 512, 0, stream>>>(xproj, whh1p, h1, cnt + 0 * 32);
  // layer 2
  k_gemm<0><<<dim3(BT / 128, GP / 128), 256, 0, stream>>>(
      h1, KP, wih2p, KP, xproj, GP, bias2, nullptr, nullptr);
  k_rec<<<160, 512, 0, stream>>>(xproj, whh2p, h2, cnt + 1 * 32);
  // layer 3
  k_gemm<0><<<dim3(BT / 128, GP / 128), 256, 0, stream>>>(
      h2, KP, wih3p, KP, xproj, GP, bias3, nullptr, nullptr);
  k_rec<<<160, 512, 0, stream>>>(xproj, whh3p, h3, cnt + 2 * 32);

  // FC + poly_bias + row-sum reduction (A rows = h3 at t=15)
  k_gemm<1><<<dim3(BATCH / 128, DP / 128), 256, 0, stream>>>(
      h3 + (size_t)15 * KP, (long)16 * KP, wfcp, KP, outb, DIM, bfc, x, sums);

  k_final<<<(BATCH * DIM + 255) / 256, 256, 0, stream>>>(outb, sums, (float*)d_out);
}